// Round 1
// baseline (339.277 us; speedup 1.0000x reference)
//
#include <hip/hip_runtime.h>
#include <math.h>

#define DM 256
#define DS 16
#define DI 512
#define BB 4
#define LL 2048
#define NC 16
#define CH (LL / NC)

// ---------------------------------------------------------------------------
// K1: xz_t[b][l][c] = sum_m W_in[c][m] * x[b][m][l]   (c in 0..1023)
// 64x64 tile, K-chunk 16, 4x4 microtile, 256 threads
// ---------------------------------------------------------------------------
__global__ __launch_bounds__(256) void k_gemm_in(const float* __restrict__ W,
                                                 const float* __restrict__ x,
                                                 float* __restrict__ xz_t) {
    __shared__ float lw[64][17];  // [c][k]
    __shared__ float lx[16][65];  // [k][l]
    const int b = blockIdx.z;
    const int c0 = blockIdx.y * 64;
    const int l0 = blockIdx.x * 64;
    const int t = threadIdx.x;
    const int tx = t & 15, ty = t >> 4;
    float acc[4][4] = {};
    const float* xb = x + (size_t)b * DM * LL;
    for (int k0 = 0; k0 < DM; k0 += 16) {
#pragma unroll
        for (int i = 0; i < 4; i++) {
            int idx = t + i * 256;
            int r = idx >> 4, cc = idx & 15;
            lw[r][cc] = W[(size_t)(c0 + r) * DM + k0 + cc];
        }
#pragma unroll
        for (int i = 0; i < 4; i++) {
            int idx = t + i * 256;
            int r = idx >> 6, cc = idx & 63;
            lx[r][cc] = xb[(size_t)(k0 + r) * LL + l0 + cc];
        }
        __syncthreads();
#pragma unroll
        for (int kk = 0; kk < 16; kk++) {
            float aw[4], xv[4];
#pragma unroll
            for (int i = 0; i < 4; i++) aw[i] = lw[ty * 4 + i][kk];
#pragma unroll
            for (int j = 0; j < 4; j++) xv[j] = lx[kk][tx * 4 + j];
#pragma unroll
            for (int i = 0; i < 4; i++)
#pragma unroll
                for (int j = 0; j < 4; j++) acc[i][j] += aw[i] * xv[j];
        }
        __syncthreads();
    }
    float* ob = xz_t + (size_t)b * LL * 1024;
#pragma unroll
    for (int j = 0; j < 4; j++) {
        int l = l0 + tx * 4 + j;
        float4 v = make_float4(acc[0][j], acc[1][j], acc[2][j], acc[3][j]);
        *(float4*)(ob + (size_t)l * 1024 + c0 + ty * 4) = v;
    }
}

// ---------------------------------------------------------------------------
// K2: depthwise conv k=3 (cross-correlation, pad 1) + bias + silu
// u_t[b][l][d] from xz_t[b][l][0..511]
// ---------------------------------------------------------------------------
__global__ __launch_bounds__(256) void k_conv(const float* __restrict__ xz_t,
                                              const float* __restrict__ Wdw,
                                              const float* __restrict__ bdw,
                                              float* __restrict__ u_t) {
    int idx = blockIdx.x * 256 + threadIdx.x;  // over B*L*DI = 4.19M
    int d = idx & 511;
    int l = (idx >> 9) & (LL - 1);
    int b = idx >> 20;
    const float* base = xz_t + (size_t)b * LL * 1024;
    float w0 = Wdw[d * 3 + 0], w1 = Wdw[d * 3 + 1], w2 = Wdw[d * 3 + 2];
    float v = bdw[d] + w1 * base[(size_t)l * 1024 + d];
    if (l > 0) v += w0 * base[(size_t)(l - 1) * 1024 + d];
    if (l < LL - 1) v += w2 * base[(size_t)(l + 1) * 1024 + d];
    float sig = 1.f / (1.f + __expf(-v));
    u_t[idx] = v * sig;
}

// ---------------------------------------------------------------------------
// K3: xdbl[b][l][c] = sum_d Wx[c][d] * u_t[b][l][d]   (c in 0..47)
// block: 32 l's, 256 threads: 8 c-groups x 32 l, 6 c per thread
// ---------------------------------------------------------------------------
__global__ __launch_bounds__(256) void k_xdbl(const float* __restrict__ u_t,
                                              const float* __restrict__ Wx,
                                              float* __restrict__ xdbl) {
    __shared__ float lu[32][65];
    __shared__ float lw[48][65];
    const int b = blockIdx.y;
    const int l0 = blockIdx.x * 32;
    const int t = threadIdx.x;
    const int lq = t & 31, cg = t >> 5;
    float acc[6] = {};
    for (int k0 = 0; k0 < DI; k0 += 64) {
#pragma unroll
        for (int i = 0; i < 8; i++) {
            int idx = t + i * 256;
            int r = idx >> 6, cc = idx & 63;
            lu[r][cc] = u_t[((size_t)b * LL + l0 + r) * DI + k0 + cc];
        }
#pragma unroll
        for (int i = 0; i < 12; i++) {
            int idx = t + i * 256;
            int r = idx >> 6, cc = idx & 63;
            lw[r][cc] = Wx[(size_t)r * DI + k0 + cc];
        }
        __syncthreads();
#pragma unroll
        for (int kk = 0; kk < 64; kk++) {
            float uv = lu[lq][kk];
#pragma unroll
            for (int i = 0; i < 6; i++) acc[i] += lw[cg * 6 + i][kk] * uv;
        }
        __syncthreads();
    }
#pragma unroll
    for (int i = 0; i < 6; i++)
        xdbl[((size_t)b * LL + l0 + lq) * 48 + cg * 6 + i] = acc[i];
}

// ---------------------------------------------------------------------------
// K4: delta_t[b][l][d] = softplus(b_dt[d] + sum_r Wdt[d][r]*dt_lr[b][l][r])
// block per (b,l), 256 threads, 2 d each
// ---------------------------------------------------------------------------
__global__ __launch_bounds__(256) void k_delta(const float* __restrict__ xdbl,
                                               const float* __restrict__ Wdt,
                                               const float* __restrict__ bdt,
                                               float* __restrict__ delta_t) {
    const int bl = blockIdx.x;  // b*LL + l
    __shared__ float xd[16];
    if (threadIdx.x < 16) xd[threadIdx.x] = xdbl[(size_t)bl * 48 + threadIdx.x];
    __syncthreads();
#pragma unroll
    for (int h = 0; h < 2; h++) {
        int d = threadIdx.x + h * 256;
        float acc = bdt[d];
        const float4* wr = (const float4*)(Wdt + (size_t)d * 16);
#pragma unroll
        for (int q = 0; q < 4; q++) {
            float4 w = wr[q];
            acc += w.x * xd[q * 4 + 0] + w.y * xd[q * 4 + 1] + w.z * xd[q * 4 + 2] +
                   w.w * xd[q * 4 + 3];
        }
        float sp = fmaxf(acc, 0.f) + log1pf(__expf(-fabsf(acc)));
        delta_t[(size_t)bl * 512 + d] = sp;
    }
}

// ---------------------------------------------------------------------------
// K5a: per-chunk local scan (h0=0): hend[b][d][c][n], dsum[b][d][c]
// block: 256 threads = 16 d-groups x 16 n. grid (NC, DI/16, B)
// ---------------------------------------------------------------------------
__global__ __launch_bounds__(256) void k_scanA(const float* __restrict__ delta_t,
                                               const float* __restrict__ xdbl,
                                               const float* __restrict__ u_t,
                                               const float* __restrict__ A_log,
                                               float* __restrict__ hend,
                                               float* __restrict__ dsum) {
    const int n = threadIdx.x & 15;
    const int dg = threadIdx.x >> 4;
    const int d = blockIdx.y * 16 + dg;
    const int b = blockIdx.z;
    const int c = blockIdx.x;
    const float Av = -__expf(A_log[d * 16 + n]);
    const float* dl = delta_t + (size_t)b * LL * 512 + d;
    const float* ul = u_t + (size_t)b * LL * 512 + d;
    const float* Bl = xdbl + (size_t)b * LL * 48 + 16 + n;
    float h = 0.f, ds = 0.f;
    const int l0 = c * CH;
    for (int s = 0; s < CH; s++) {
        size_t l = l0 + s;
        float de = dl[l * 512];
        float uu = ul[l * 512];
        float Bv = Bl[l * 48];
        h = __expf(de * Av) * h + de * Bv * uu;
        ds += de;
    }
    size_t idx = ((size_t)b * 512 + d) * NC + c;
    hend[idx * 16 + n] = h;
    if (n == 0) dsum[idx] = ds;
}

// ---------------------------------------------------------------------------
// K5b: sequential chunk fix-up: hinit[b][d][c][n]
// ---------------------------------------------------------------------------
__global__ __launch_bounds__(256) void k_scanB(const float* __restrict__ A_log,
                                               const float* __restrict__ dsum,
                                               const float* __restrict__ hend,
                                               float* __restrict__ hinit) {
    int idx = blockIdx.x * 256 + threadIdx.x;  // over B*DI*16 = 32768
    int n = idx & 15;
    int bd = idx >> 4;
    int d = bd & 511;
    float Av = -__expf(A_log[d * 16 + n]);
    float h = 0.f;
    for (int c = 0; c < NC; c++) {
        hinit[((size_t)bd * NC + c) * 16 + n] = h;
        float ds = dsum[(size_t)bd * NC + c];
        h = __expf(ds * Av) * h + hend[((size_t)bd * NC + c) * 16 + n];
    }
}

// ---------------------------------------------------------------------------
// K5c: replay chunk with correct hinit, emit y_t[b][l][d] = (y + D*u)*silu(z)
// ---------------------------------------------------------------------------
__global__ __launch_bounds__(256) void k_scanC(const float* __restrict__ delta_t,
                                               const float* __restrict__ xdbl,
                                               const float* __restrict__ u_t,
                                               const float* __restrict__ xz_t,
                                               const float* __restrict__ A_log,
                                               const float* __restrict__ Dp,
                                               const float* __restrict__ hinit,
                                               float* __restrict__ y_t) {
    const int n = threadIdx.x & 15;
    const int dg = threadIdx.x >> 4;
    const int d = blockIdx.y * 16 + dg;
    const int b = blockIdx.z;
    const int c = blockIdx.x;
    const float Av = -__expf(A_log[d * 16 + n]);
    const float Dv = Dp[d];
    const float* dl = delta_t + (size_t)b * LL * 512 + d;
    const float* ul = u_t + (size_t)b * LL * 512 + d;
    const float* Bl = xdbl + (size_t)b * LL * 48 + 16 + n;
    const float* Cl = xdbl + (size_t)b * LL * 48 + 32 + n;
    const float* zl = xz_t + (size_t)b * LL * 1024 + 512 + d;
    float* yb = y_t + (size_t)b * LL * 512 + d;
    float h = hinit[(((size_t)b * 512 + d) * NC + c) * 16 + n];
    const int l0 = c * CH;
    for (int s = 0; s < CH; s++) {
        size_t l = l0 + s;
        float de = dl[l * 512];
        float uu = ul[l * 512];
        float Bv = Bl[l * 48];
        h = __expf(de * Av) * h + de * Bv * uu;
        float yc = h * Cl[l * 48];
        yc += __shfl_xor(yc, 1);
        yc += __shfl_xor(yc, 2);
        yc += __shfl_xor(yc, 4);
        yc += __shfl_xor(yc, 8);
        if (n == 0) {
            float zz = zl[l * 1024];
            float sig = 1.f / (1.f + __expf(-zz));
            yb[l * 512] = (yc + Dv * uu) * (zz * sig);
        }
    }
}

// ---------------------------------------------------------------------------
// K6: out[b][o][l] = sum_d W_out[o][d]*y_t[b][l][d] + x[b][o][l]
// 64x64 tile, K-chunk 64, 4x4 microtile
// ---------------------------------------------------------------------------
__global__ __launch_bounds__(256) void k_gemm_out(const float* __restrict__ W,
                                                  const float* __restrict__ y_t,
                                                  const float* __restrict__ x,
                                                  float* __restrict__ out) {
    __shared__ float lw[64][65];  // [o][k]
    __shared__ float ly[64][65];  // [l][k]
    const int b = blockIdx.z;
    const int o0 = blockIdx.y * 64;
    const int l0 = blockIdx.x * 64;
    const int t = threadIdx.x;
    const int tx = t & 15, ty = t >> 4;
    float acc[4][4] = {};
    for (int k0 = 0; k0 < DI; k0 += 64) {
#pragma unroll
        for (int i = 0; i < 16; i++) {
            int idx = t + i * 256;
            int r = idx >> 6, cc = idx & 63;
            lw[r][cc] = W[(size_t)(o0 + r) * DI + k0 + cc];
            ly[r][cc] = y_t[((size_t)b * LL + l0 + r) * DI + k0 + cc];
        }
        __syncthreads();
#pragma unroll
        for (int kk = 0; kk < 64; kk++) {
            float aw[4], yv[4];
#pragma unroll
            for (int i = 0; i < 4; i++) aw[i] = lw[ty * 4 + i][kk];
#pragma unroll
            for (int j = 0; j < 4; j++) yv[j] = ly[tx * 4 + j][kk];
#pragma unroll
            for (int i = 0; i < 4; i++)
#pragma unroll
                for (int j = 0; j < 4; j++) acc[i][j] += aw[i] * yv[j];
        }
        __syncthreads();
    }
#pragma unroll
    for (int i = 0; i < 4; i++) {
        int o = o0 + ty * 4 + i;
        size_t base = ((size_t)b * DM + o) * LL + l0 + tx * 4;
        float4 r = *(const float4*)(x + base);
        float4 v = make_float4(acc[i][0] + r.x, acc[i][1] + r.y, acc[i][2] + r.z,
                               acc[i][3] + r.w);
        *(float4*)(out + base) = v;
    }
}

// ---------------------------------------------------------------------------
extern "C" void kernel_launch(void* const* d_in, const int* in_sizes, int n_in,
                              void* d_out, int out_size, void* d_ws, size_t ws_size,
                              hipStream_t stream) {
    const float* x = (const float*)d_in[0];
    const float* W_in = (const float*)d_in[1];
    const float* W_dw = (const float*)d_in[2];
    const float* b_dw = (const float*)d_in[3];
    const float* W_x = (const float*)d_in[4];
    const float* W_dt = (const float*)d_in[5];
    const float* b_dt = (const float*)d_in[6];
    const float* A_log = (const float*)d_in[7];
    const float* Dp = (const float*)d_in[8];
    const float* W_out = (const float*)d_in[9];
    float* out = (float*)d_out;

    float* ws = (float*)d_ws;
    float* xz_t = ws;                         // B*L*1024 = 8388608
    float* u_t = xz_t + (size_t)BB * LL * 1024;   // B*L*512
    float* xdbl = u_t + (size_t)BB * LL * 512;    // B*L*48
    float* delta_t = xdbl + (size_t)BB * LL * 48; // B*L*512
    float* y_t = delta_t + (size_t)BB * LL * 512; // B*L*512
    float* hend = y_t + (size_t)BB * LL * 512;    // B*512*NC*16
    float* dsum = hend + (size_t)BB * 512 * NC * 16;  // B*512*NC
    float* hinit = dsum + (size_t)BB * 512 * NC;      // B*512*NC*16

    k_gemm_in<<<dim3(LL / 64, 1024 / 64, BB), 256, 0, stream>>>(W_in, x, xz_t);
    k_conv<<<(BB * LL * DI) / 256, 256, 0, stream>>>(xz_t, W_dw, b_dw, u_t);
    k_xdbl<<<dim3(LL / 32, BB), 256, 0, stream>>>(u_t, W_x, xdbl);
    k_delta<<<BB * LL, 256, 0, stream>>>(xdbl, W_dt, b_dt, delta_t);
    k_scanA<<<dim3(NC, DI / 16, BB), 256, 0, stream>>>(delta_t, xdbl, u_t, A_log, hend,
                                                       dsum);
    k_scanB<<<(BB * DI * 16) / 256, 256, 0, stream>>>(A_log, dsum, hend, hinit);
    k_scanC<<<dim3(NC, DI / 16, BB), 256, 0, stream>>>(delta_t, xdbl, u_t, xz_t, A_log,
                                                       Dp, hinit, y_t);
    k_gemm_out<<<dim3(LL / 64, DM / 64, BB), 256, 0, stream>>>(W_out, y_t, x, out);
}

// Round 2
// 260.670 us; speedup vs baseline: 1.3016x; 1.3016x over previous
//
#include <hip/hip_runtime.h>
#include <math.h>

#define DM 256
#define DS 16
#define DI 512
#define BB 4
#define LL 2048
#define NC 64
#define CH (LL / NC)

// ---------------------------------------------------------------------------
// K1: xz_t[b][l][c] = sum_m W_in[c][m] * x[b][m][l]   (c in 0..1023)
// 64x64 tile, K-chunk 16, 4x4 microtile, 256 threads
// ---------------------------------------------------------------------------
__global__ __launch_bounds__(256) void k_gemm_in(const float* __restrict__ W,
                                                 const float* __restrict__ x,
                                                 float* __restrict__ xz_t) {
    __shared__ float lw[64][17];  // [c][k]
    __shared__ float lx[16][65];  // [k][l]
    const int b = blockIdx.z;
    const int c0 = blockIdx.y * 64;
    const int l0 = blockIdx.x * 64;
    const int t = threadIdx.x;
    const int tx = t & 15, ty = t >> 4;
    float acc[4][4] = {};
    const float* xb = x + (size_t)b * DM * LL;
    for (int k0 = 0; k0 < DM; k0 += 16) {
#pragma unroll
        for (int i = 0; i < 4; i++) {
            int idx = t + i * 256;
            int r = idx >> 4, cc = idx & 15;
            lw[r][cc] = W[(size_t)(c0 + r) * DM + k0 + cc];
        }
#pragma unroll
        for (int i = 0; i < 4; i++) {
            int idx = t + i * 256;
            int r = idx >> 6, cc = idx & 63;
            lx[r][cc] = xb[(size_t)(k0 + r) * LL + l0 + cc];
        }
        __syncthreads();
#pragma unroll
        for (int kk = 0; kk < 16; kk++) {
            float aw[4], xv[4];
#pragma unroll
            for (int i = 0; i < 4; i++) aw[i] = lw[ty * 4 + i][kk];
#pragma unroll
            for (int j = 0; j < 4; j++) xv[j] = lx[kk][tx * 4 + j];
#pragma unroll
            for (int i = 0; i < 4; i++)
#pragma unroll
                for (int j = 0; j < 4; j++) acc[i][j] += aw[i] * xv[j];
        }
        __syncthreads();
    }
    float* ob = xz_t + (size_t)b * LL * 1024;
#pragma unroll
    for (int j = 0; j < 4; j++) {
        int l = l0 + tx * 4 + j;
        float4 v = make_float4(acc[0][j], acc[1][j], acc[2][j], acc[3][j]);
        *(float4*)(ob + (size_t)l * 1024 + c0 + ty * 4) = v;
    }
}

// ---------------------------------------------------------------------------
// K2: depthwise conv k=3 (cross-correlation, pad 1) + bias + silu
// ---------------------------------------------------------------------------
__global__ __launch_bounds__(256) void k_conv(const float* __restrict__ xz_t,
                                              const float* __restrict__ Wdw,
                                              const float* __restrict__ bdw,
                                              float* __restrict__ u_t) {
    int idx = blockIdx.x * 256 + threadIdx.x;  // over B*L*DI = 4.19M
    int d = idx & 511;
    int l = (idx >> 9) & (LL - 1);
    int b = idx >> 20;
    const float* base = xz_t + (size_t)b * LL * 1024;
    float w0 = Wdw[d * 3 + 0], w1 = Wdw[d * 3 + 1], w2 = Wdw[d * 3 + 2];
    float v = bdw[d] + w1 * base[(size_t)l * 1024 + d];
    if (l > 0) v += w0 * base[(size_t)(l - 1) * 1024 + d];
    if (l < LL - 1) v += w2 * base[(size_t)(l + 1) * 1024 + d];
    float sig = 1.f / (1.f + __expf(-v));
    u_t[idx] = v * sig;
}

// ---------------------------------------------------------------------------
// K3: xdbl[b][l][c] = sum_d Wx[c][d] * u_t[b][l][d]   (c in 0..47)
// ---------------------------------------------------------------------------
__global__ __launch_bounds__(256) void k_xdbl(const float* __restrict__ u_t,
                                              const float* __restrict__ Wx,
                                              float* __restrict__ xdbl) {
    __shared__ float lu[32][65];
    __shared__ float lw[48][65];
    const int b = blockIdx.y;
    const int l0 = blockIdx.x * 32;
    const int t = threadIdx.x;
    const int lq = t & 31, cg = t >> 5;
    float acc[6] = {};
    for (int k0 = 0; k0 < DI; k0 += 64) {
#pragma unroll
        for (int i = 0; i < 8; i++) {
            int idx = t + i * 256;
            int r = idx >> 6, cc = idx & 63;
            lu[r][cc] = u_t[((size_t)b * LL + l0 + r) * DI + k0 + cc];
        }
#pragma unroll
        for (int i = 0; i < 12; i++) {
            int idx = t + i * 256;
            int r = idx >> 6, cc = idx & 63;
            lw[r][cc] = Wx[(size_t)r * DI + k0 + cc];
        }
        __syncthreads();
#pragma unroll
        for (int kk = 0; kk < 64; kk++) {
            float uv = lu[lq][kk];
#pragma unroll
            for (int i = 0; i < 6; i++) acc[i] += lw[cg * 6 + i][kk] * uv;
        }
        __syncthreads();
    }
#pragma unroll
    for (int i = 0; i < 6; i++)
        xdbl[((size_t)b * LL + l0 + lq) * 48 + cg * 6 + i] = acc[i];
}

// ---------------------------------------------------------------------------
// K4: delta_t[b][l][d] = softplus(b_dt[d] + sum_r Wdt[d][r]*dt_lr[b][l][r])
// ---------------------------------------------------------------------------
__global__ __launch_bounds__(256) void k_delta(const float* __restrict__ xdbl,
                                               const float* __restrict__ Wdt,
                                               const float* __restrict__ bdt,
                                               float* __restrict__ delta_t) {
    const int bl = blockIdx.x;  // b*LL + l
    __shared__ float xd[16];
    if (threadIdx.x < 16) xd[threadIdx.x] = xdbl[(size_t)bl * 48 + threadIdx.x];
    __syncthreads();
#pragma unroll
    for (int h = 0; h < 2; h++) {
        int d = threadIdx.x + h * 256;
        float acc = bdt[d];
        const float4* wr = (const float4*)(Wdt + (size_t)d * 16);
#pragma unroll
        for (int q = 0; q < 4; q++) {
            float4 w = wr[q];
            acc += w.x * xd[q * 4 + 0] + w.y * xd[q * 4 + 1] + w.z * xd[q * 4 + 2] +
                   w.w * xd[q * 4 + 3];
        }
        float sp = fmaxf(acc, 0.f) + log1pf(__expf(-fabsf(acc)));
        delta_t[(size_t)bl * 512 + d] = sp;
    }
}

// ---------------------------------------------------------------------------
// K5a: per-chunk local scan, thread-per-d, h[16] in registers.
// grid (NC, DI/256, B), block 256. Outputs: hend[b][c][d][16], dsum[b][c][d].
// ---------------------------------------------------------------------------
__global__ __launch_bounds__(256) void k_scanA(const float* __restrict__ delta_t,
                                               const float* __restrict__ xdbl,
                                               const float* __restrict__ u_t,
                                               const float* __restrict__ A_log,
                                               float* __restrict__ hend,
                                               float* __restrict__ dsum) {
    __shared__ float Bt[CH][16];
    const int t = threadIdx.x;
    const int d = blockIdx.y * 256 + t;
    const int b = blockIdx.z;
    const int c = blockIdx.x;
    const int l0 = c * CH;
    const size_t bl0 = (size_t)b * LL + l0;
    // stage B_ssm chunk: CH*16 floats = 128 float4
    if (t < 128) {
        int l = t >> 2, n0 = (t & 3) * 4;
        *(float4*)&Bt[l][n0] = *(const float4*)(xdbl + (bl0 + l) * 48 + 16 + n0);
    }
    float Av[16];
    {
        const float4* Ar = (const float4*)(A_log + (size_t)d * 16);
#pragma unroll
        for (int q = 0; q < 4; q++) {
            float4 a = Ar[q];
            Av[q * 4 + 0] = -__expf(a.x);
            Av[q * 4 + 1] = -__expf(a.y);
            Av[q * 4 + 2] = -__expf(a.z);
            Av[q * 4 + 3] = -__expf(a.w);
        }
    }
    __syncthreads();
    const float* dl = delta_t + bl0 * 512 + d;
    const float* ul = u_t + bl0 * 512 + d;
    float h[16] = {};
    float ds = 0.f;
#pragma unroll 4
    for (int s = 0; s < CH; s++) {
        float de = dl[(size_t)s * 512];
        float uu = ul[(size_t)s * 512];
        float du = de * uu;
        ds += de;
#pragma unroll
        for (int n = 0; n < 16; n++) {
            float dA = __expf(de * Av[n]);
            h[n] = dA * h[n] + du * Bt[s][n];
        }
    }
    size_t base = ((size_t)b * NC + c) * 512 + d;
    float4* hp = (float4*)(hend + base * 16);
#pragma unroll
    for (int q = 0; q < 4; q++)
        hp[q] = make_float4(h[q * 4 + 0], h[q * 4 + 1], h[q * 4 + 2], h[q * 4 + 3]);
    dsum[base] = ds;
}

// ---------------------------------------------------------------------------
// K5b: sequential chunk fix-up over NC chunks: hinit[b][c][d][16]
// ---------------------------------------------------------------------------
__global__ __launch_bounds__(256) void k_scanB(const float* __restrict__ A_log,
                                               const float* __restrict__ dsum,
                                               const float* __restrict__ hend,
                                               float* __restrict__ hinit) {
    int idx = blockIdx.x * 256 + threadIdx.x;  // over B*DI*16 = 32768
    int n = idx & 15;
    int d = (idx >> 4) & 511;
    int b = idx >> 13;
    float Av = -__expf(A_log[d * 16 + n]);
    float h = 0.f;
    for (int c = 0; c < NC; c++) {
        size_t base = ((size_t)b * NC + c) * 512 + d;
        hinit[base * 16 + n] = h;
        float dsv = dsum[base];
        h = __expf(dsv * Av) * h + hend[base * 16 + n];
    }
}

// ---------------------------------------------------------------------------
// K5c: replay with correct hinit; emit y_t[b][l][d] = (h.C + D*u)*silu(z)
// ---------------------------------------------------------------------------
__global__ __launch_bounds__(256) void k_scanC(const float* __restrict__ delta_t,
                                               const float* __restrict__ xdbl,
                                               const float* __restrict__ u_t,
                                               const float* __restrict__ xz_t,
                                               const float* __restrict__ A_log,
                                               const float* __restrict__ Dp,
                                               const float* __restrict__ hinit,
                                               float* __restrict__ y_t) {
    __shared__ float Bt[CH][16];
    __shared__ float Ct[CH][16];
    const int t = threadIdx.x;
    const int d = blockIdx.y * 256 + t;
    const int b = blockIdx.z;
    const int c = blockIdx.x;
    const int l0 = c * CH;
    const size_t bl0 = (size_t)b * LL + l0;
    if (t < 128) {
        int l = t >> 2, n0 = (t & 3) * 4;
        *(float4*)&Bt[l][n0] = *(const float4*)(xdbl + (bl0 + l) * 48 + 16 + n0);
    } else {
        int t2 = t - 128;
        int l = t2 >> 2, n0 = (t2 & 3) * 4;
        *(float4*)&Ct[l][n0] = *(const float4*)(xdbl + (bl0 + l) * 48 + 32 + n0);
    }
    float Av[16];
    {
        const float4* Ar = (const float4*)(A_log + (size_t)d * 16);
#pragma unroll
        for (int q = 0; q < 4; q++) {
            float4 a = Ar[q];
            Av[q * 4 + 0] = -__expf(a.x);
            Av[q * 4 + 1] = -__expf(a.y);
            Av[q * 4 + 2] = -__expf(a.z);
            Av[q * 4 + 3] = -__expf(a.w);
        }
    }
    float h[16];
    {
        size_t base = ((size_t)b * NC + c) * 512 + d;
        const float4* hp = (const float4*)(hinit + base * 16);
#pragma unroll
        for (int q = 0; q < 4; q++) {
            float4 v = hp[q];
            h[q * 4 + 0] = v.x;
            h[q * 4 + 1] = v.y;
            h[q * 4 + 2] = v.z;
            h[q * 4 + 3] = v.w;
        }
    }
    __syncthreads();
    const float* dl = delta_t + bl0 * 512 + d;
    const float* ul = u_t + bl0 * 512 + d;
    const float* zl = xz_t + bl0 * 1024 + 512 + d;
    float* yl = y_t + bl0 * 512 + d;
    const float Dv = Dp[d];
#pragma unroll 4
    for (int s = 0; s < CH; s++) {
        float de = dl[(size_t)s * 512];
        float uu = ul[(size_t)s * 512];
        float zz = zl[(size_t)s * 1024];
        float du = de * uu;
        float dot = 0.f;
#pragma unroll
        for (int n = 0; n < 16; n++) {
            float dA = __expf(de * Av[n]);
            h[n] = dA * h[n] + du * Bt[s][n];
            dot += h[n] * Ct[s][n];
        }
        float sig = 1.f / (1.f + __expf(-zz));
        yl[(size_t)s * 512] = (dot + Dv * uu) * (zz * sig);
    }
}

// ---------------------------------------------------------------------------
// K6: out[b][o][l] = sum_d W_out[o][d]*y_t[b][l][d] + x[b][o][l]
// ---------------------------------------------------------------------------
__global__ __launch_bounds__(256) void k_gemm_out(const float* __restrict__ W,
                                                  const float* __restrict__ y_t,
                                                  const float* __restrict__ x,
                                                  float* __restrict__ out) {
    __shared__ float lw[64][65];  // [o][k]
    __shared__ float ly[64][65];  // [l][k]
    const int b = blockIdx.z;
    const int o0 = blockIdx.y * 64;
    const int l0 = blockIdx.x * 64;
    const int t = threadIdx.x;
    const int tx = t & 15, ty = t >> 4;
    float acc[4][4] = {};
    for (int k0 = 0; k0 < DI; k0 += 64) {
#pragma unroll
        for (int i = 0; i < 16; i++) {
            int idx = t + i * 256;
            int r = idx >> 6, cc = idx & 63;
            lw[r][cc] = W[(size_t)(o0 + r) * DI + k0 + cc];
            ly[r][cc] = y_t[((size_t)b * LL + l0 + r) * DI + k0 + cc];
        }
        __syncthreads();
#pragma unroll
        for (int kk = 0; kk < 64; kk++) {
            float aw[4], yv[4];
#pragma unroll
            for (int i = 0; i < 4; i++) aw[i] = lw[ty * 4 + i][kk];
#pragma unroll
            for (int j = 0; j < 4; j++) yv[j] = ly[tx * 4 + j][kk];
#pragma unroll
            for (int i = 0; i < 4; i++)
#pragma unroll
                for (int j = 0; j < 4; j++) acc[i][j] += aw[i] * yv[j];
        }
        __syncthreads();
    }
#pragma unroll
    for (int i = 0; i < 4; i++) {
        int o = o0 + ty * 4 + i;
        size_t base = ((size_t)b * DM + o) * LL + l0 + tx * 4;
        float4 r = *(const float4*)(x + base);
        float4 v = make_float4(acc[i][0] + r.x, acc[i][1] + r.y, acc[i][2] + r.z,
                               acc[i][3] + r.w);
        *(float4*)(out + base) = v;
    }
}

// ---------------------------------------------------------------------------
extern "C" void kernel_launch(void* const* d_in, const int* in_sizes, int n_in,
                              void* d_out, int out_size, void* d_ws, size_t ws_size,
                              hipStream_t stream) {
    const float* x = (const float*)d_in[0];
    const float* W_in = (const float*)d_in[1];
    const float* W_dw = (const float*)d_in[2];
    const float* b_dw = (const float*)d_in[3];
    const float* W_x = (const float*)d_in[4];
    const float* W_dt = (const float*)d_in[5];
    const float* b_dt = (const float*)d_in[6];
    const float* A_log = (const float*)d_in[7];
    const float* Dp = (const float*)d_in[8];
    const float* W_out = (const float*)d_in[9];
    float* out = (float*)d_out;

    float* ws = (float*)d_ws;
    float* xz_t = ws;                               // B*L*1024
    float* u_t = xz_t + (size_t)BB * LL * 1024;     // B*L*512
    float* xdbl = u_t + (size_t)BB * LL * 512;      // B*L*48
    float* delta_t = xdbl + (size_t)BB * LL * 48;   // B*L*512
    float* y_t = delta_t + (size_t)BB * LL * 512;   // B*L*512
    // hend aliases y_t: hend is dead after k_scanB, before k_scanC writes y_t
    float* hend = y_t;                              // B*NC*512*16 (2.1M <= 4.2M)
    float* dsum = y_t + (size_t)BB * LL * 512;      // B*NC*512
    float* hinit = dsum + (size_t)BB * NC * 512;    // B*NC*512*16

    k_gemm_in<<<dim3(LL / 64, 1024 / 64, BB), 256, 0, stream>>>(W_in, x, xz_t);
    k_conv<<<(BB * LL * DI) / 256, 256, 0, stream>>>(xz_t, W_dw, b_dw, u_t);
    k_xdbl<<<dim3(LL / 32, BB), 256, 0, stream>>>(u_t, W_x, xdbl);
    k_delta<<<BB * LL, 256, 0, stream>>>(xdbl, W_dt, b_dt, delta_t);
    k_scanA<<<dim3(NC, DI / 256, BB), 256, 0, stream>>>(delta_t, xdbl, u_t, A_log,
                                                        hend, dsum);
    k_scanB<<<(BB * DI * 16) / 256, 256, 0, stream>>>(A_log, dsum, hend, hinit);
    k_scanC<<<dim3(NC, DI / 256, BB), 256, 0, stream>>>(delta_t, xdbl, u_t, xz_t,
                                                        A_log, Dp, hinit, y_t);
    k_gemm_out<<<dim3(LL / 64, DM / 64, BB), 256, 0, stream>>>(W_out, y_t, x, out);
}

// Round 3
// 156.164 us; speedup vs baseline: 2.1726x; 1.6692x over previous
//
#include <hip/hip_runtime.h>
#include <math.h>

#define DM 256
#define DS 16
#define DI 512
#define BB 4
#define LL 2048
#define NC 64
#define CH (LL / NC)

typedef short bf16x8 __attribute__((ext_vector_type(8)));
typedef float f32x4 __attribute__((ext_vector_type(4)));
typedef unsigned short ushort_t;

__device__ inline unsigned short f2bf(float f) {
    union { float f; unsigned u; } v;
    v.f = f;
    unsigned r = (v.u + 0x7FFF + ((v.u >> 16) & 1)) >> 16;
    return (unsigned short)r;
}

// ---------------------------------------------------------------------------
// K0a: elementwise fp32 -> bf16 convert (4 elems/thread)
// ---------------------------------------------------------------------------
__global__ __launch_bounds__(256) void k_cvt4(const float* __restrict__ s,
                                              ushort_t* __restrict__ d, int n4) {
    int i = blockIdx.x * 256 + threadIdx.x;
    if (i >= n4) return;
    float4 v = ((const float4*)s)[i];
    unsigned o0 = (unsigned)f2bf(v.x) | ((unsigned)f2bf(v.y) << 16);
    unsigned o1 = (unsigned)f2bf(v.z) | ((unsigned)f2bf(v.w) << 16);
    ((uint2*)d)[i] = make_uint2(o0, o1);
}

// ---------------------------------------------------------------------------
// K0b: x[b][m][l] fp32 -> xt[b][l][m] bf16 (64x64 LDS transpose)
// ---------------------------------------------------------------------------
__global__ __launch_bounds__(256) void k_cvt_x(const float* __restrict__ x,
                                               ushort_t* __restrict__ xt) {
    __shared__ float tile[64][65];
    const int b = blockIdx.z;
    const int m0 = blockIdx.y * 64;
    const int l0 = blockIdx.x * 64;
    const float* xb = x + ((size_t)b * DM + m0) * LL + l0;
    const int t = threadIdx.x;
#pragma unroll
    for (int i = 0; i < 16; i++) {
        int idx = t + i * 256;
        int r = idx >> 6, c = idx & 63;
        tile[r][c] = xb[(size_t)r * LL + c];
    }
    __syncthreads();
    ushort_t* ob = xt + ((size_t)b * LL + l0) * DM + m0;
#pragma unroll
    for (int i = 0; i < 16; i++) {
        int idx = t + i * 256;
        int r = idx >> 6, c = idx & 63;  // r: l-row, c: m-col
        ob[(size_t)r * DM + c] = f2bf(tile[c][r]);
    }
}

// ---------------------------------------------------------------------------
// K1: MFMA GEMM  xz_t[b][l][c] = sum_m xt[b][l][m] * W_in[c][m]
// A-operand = xt rows(l), B-operand = W_in rows(c). 128x128 tile, BK=64.
// 4 waves (2x2), wave tile 64x64, mfma_f32_16x16x32_bf16.
// ---------------------------------------------------------------------------
__global__ __launch_bounds__(256) void k_gemm_in(const ushort_t* __restrict__ xt,
                                                 const ushort_t* __restrict__ Wb,
                                                 float* __restrict__ xz_t) {
    __shared__ short As[128 * 64];
    __shared__ short Bs[128 * 64];
    const int b = blockIdx.z;
    const int l0 = blockIdx.x * 128;
    const int c0 = blockIdx.y * 128;
    const int t = threadIdx.x;
    const int lane = t & 63, wv = t >> 6;
    const int wr = wv >> 1, wc = wv & 1;
    const ushort_t* xb = xt + (size_t)b * LL * DM;
    f32x4 acc[4][4] = {};
    for (int k0 = 0; k0 < DM; k0 += 64) {
#pragma unroll
        for (int i = 0; i < 4; i++) {
            int ci = t + i * 256;
            int r = ci >> 3;
            int cb = (ci & 7) * 16;
            int pd = r * 128 + (cb ^ ((r & 7) << 4));
            float4 ga = *(const float4*)((const char*)(xb + (size_t)(l0 + r) * DM + k0) + cb);
            *(float4*)((char*)As + pd) = ga;
            float4 gb = *(const float4*)((const char*)(Wb + (size_t)(c0 + r) * DM + k0) + cb);
            *(float4*)((char*)Bs + pd) = gb;
        }
        __syncthreads();
#pragma unroll
        for (int kk = 0; kk < 2; kk++) {
            const int lcb = kk * 64 + (lane >> 4) * 16;
            bf16x8 af[4], bfr[4];
#pragma unroll
            for (int mi = 0; mi < 4; mi++) {
                int r = wr * 64 + mi * 16 + (lane & 15);
                af[mi] = *(const bf16x8*)((const char*)As + r * 128 + (lcb ^ ((r & 7) << 4)));
            }
#pragma unroll
            for (int ni = 0; ni < 4; ni++) {
                int r = wc * 64 + ni * 16 + (lane & 15);
                bfr[ni] = *(const bf16x8*)((const char*)Bs + r * 128 + (lcb ^ ((r & 7) << 4)));
            }
#pragma unroll
            for (int mi = 0; mi < 4; mi++)
#pragma unroll
                for (int ni = 0; ni < 4; ni++)
                    acc[mi][ni] = __builtin_amdgcn_mfma_f32_16x16x32_bf16(
                        af[mi], bfr[ni], acc[mi][ni], 0, 0, 0);
        }
        __syncthreads();
    }
    float* ob = xz_t + (size_t)b * LL * 1024;
#pragma unroll
    for (int mi = 0; mi < 4; mi++) {
#pragma unroll
        for (int q = 0; q < 4; q++) {
            int l = l0 + wr * 64 + mi * 16 + (lane >> 4) * 4 + q;
#pragma unroll
            for (int ni = 0; ni < 4; ni++) {
                int c = c0 + wc * 64 + ni * 16 + (lane & 15);
                ob[(size_t)l * 1024 + c] = acc[mi][ni][q];
            }
        }
    }
}

// ---------------------------------------------------------------------------
// K2: depthwise conv k=3 + bias + silu (unchanged)
// ---------------------------------------------------------------------------
__global__ __launch_bounds__(256) void k_conv(const float* __restrict__ xz_t,
                                              const float* __restrict__ Wdw,
                                              const float* __restrict__ bdw,
                                              float* __restrict__ u_t) {
    int idx = blockIdx.x * 256 + threadIdx.x;
    int d = idx & 511;
    int l = (idx >> 9) & (LL - 1);
    int b = idx >> 20;
    const float* base = xz_t + (size_t)b * LL * 1024;
    float w0 = Wdw[d * 3 + 0], w1 = Wdw[d * 3 + 1], w2 = Wdw[d * 3 + 2];
    float v = bdw[d] + w1 * base[(size_t)l * 1024 + d];
    if (l > 0) v += w0 * base[(size_t)(l - 1) * 1024 + d];
    if (l < LL - 1) v += w2 * base[(size_t)(l + 1) * 1024 + d];
    float sig = 1.f / (1.f + __expf(-v));
    u_t[idx] = v * sig;
}

// ---------------------------------------------------------------------------
// K3: xdbl[b][l][c] = sum_d Wx[c][d] * u_t[b][l][d]   (c in 0..47)
// ---------------------------------------------------------------------------
__global__ __launch_bounds__(256) void k_xdbl(const float* __restrict__ u_t,
                                              const float* __restrict__ Wx,
                                              float* __restrict__ xdbl) {
    __shared__ float lu[32][65];
    __shared__ float lw[48][65];
    const int b = blockIdx.y;
    const int l0 = blockIdx.x * 32;
    const int t = threadIdx.x;
    const int lq = t & 31, cg = t >> 5;
    float acc[6] = {};
    for (int k0 = 0; k0 < DI; k0 += 64) {
#pragma unroll
        for (int i = 0; i < 8; i++) {
            int idx = t + i * 256;
            int r = idx >> 6, cc = idx & 63;
            lu[r][cc] = u_t[((size_t)b * LL + l0 + r) * DI + k0 + cc];
        }
#pragma unroll
        for (int i = 0; i < 12; i++) {
            int idx = t + i * 256;
            int r = idx >> 6, cc = idx & 63;
            lw[r][cc] = Wx[(size_t)r * DI + k0 + cc];
        }
        __syncthreads();
#pragma unroll
        for (int kk = 0; kk < 64; kk++) {
            float uv = lu[lq][kk];
#pragma unroll
            for (int i = 0; i < 6; i++) acc[i] += lw[cg * 6 + i][kk] * uv;
        }
        __syncthreads();
    }
#pragma unroll
    for (int i = 0; i < 6; i++)
        xdbl[((size_t)b * LL + l0 + lq) * 48 + cg * 6 + i] = acc[i];
}

// ---------------------------------------------------------------------------
// K4: delta_t = softplus(Wdt @ dt_lr + b_dt)
// ---------------------------------------------------------------------------
__global__ __launch_bounds__(256) void k_delta(const float* __restrict__ xdbl,
                                               const float* __restrict__ Wdt,
                                               const float* __restrict__ bdt,
                                               float* __restrict__ delta_t) {
    const int bl = blockIdx.x;
    __shared__ float xd[16];
    if (threadIdx.x < 16) xd[threadIdx.x] = xdbl[(size_t)bl * 48 + threadIdx.x];
    __syncthreads();
#pragma unroll
    for (int h = 0; h < 2; h++) {
        int d = threadIdx.x + h * 256;
        float acc = bdt[d];
        const float4* wr = (const float4*)(Wdt + (size_t)d * 16);
#pragma unroll
        for (int q = 0; q < 4; q++) {
            float4 w = wr[q];
            acc += w.x * xd[q * 4 + 0] + w.y * xd[q * 4 + 1] + w.z * xd[q * 4 + 2] +
                   w.w * xd[q * 4 + 3];
        }
        float sp = fmaxf(acc, 0.f) + log1pf(__expf(-fabsf(acc)));
        delta_t[(size_t)bl * 512 + d] = sp;
    }
}

// ---------------------------------------------------------------------------
// K5a: per-chunk local scan, thread-per-d, h[16] in registers.
// ---------------------------------------------------------------------------
__global__ __launch_bounds__(256) void k_scanA(const float* __restrict__ delta_t,
                                               const float* __restrict__ xdbl,
                                               const float* __restrict__ u_t,
                                               const float* __restrict__ A_log,
                                               float* __restrict__ hend,
                                               float* __restrict__ dsum) {
    __shared__ float Bt[CH][16];
    const int t = threadIdx.x;
    const int d = blockIdx.y * 256 + t;
    const int b = blockIdx.z;
    const int c = blockIdx.x;
    const int l0 = c * CH;
    const size_t bl0 = (size_t)b * LL + l0;
    if (t < 128) {
        int l = t >> 2, n0 = (t & 3) * 4;
        *(float4*)&Bt[l][n0] = *(const float4*)(xdbl + (bl0 + l) * 48 + 16 + n0);
    }
    float Av[16];
    {
        const float4* Ar = (const float4*)(A_log + (size_t)d * 16);
#pragma unroll
        for (int q = 0; q < 4; q++) {
            float4 a = Ar[q];
            Av[q * 4 + 0] = -__expf(a.x);
            Av[q * 4 + 1] = -__expf(a.y);
            Av[q * 4 + 2] = -__expf(a.z);
            Av[q * 4 + 3] = -__expf(a.w);
        }
    }
    __syncthreads();
    const float* dl = delta_t + bl0 * 512 + d;
    const float* ul = u_t + bl0 * 512 + d;
    float h[16] = {};
    float ds = 0.f;
#pragma unroll 4
    for (int s = 0; s < CH; s++) {
        float de = dl[(size_t)s * 512];
        float uu = ul[(size_t)s * 512];
        float du = de * uu;
        ds += de;
#pragma unroll
        for (int n = 0; n < 16; n++) {
            float dA = __expf(de * Av[n]);
            h[n] = dA * h[n] + du * Bt[s][n];
        }
    }
    size_t base = ((size_t)b * NC + c) * 512 + d;
    float4* hp = (float4*)(hend + base * 16);
#pragma unroll
    for (int q = 0; q < 4; q++)
        hp[q] = make_float4(h[q * 4 + 0], h[q * 4 + 1], h[q * 4 + 2], h[q * 4 + 3]);
    dsum[base] = ds;
}

// ---------------------------------------------------------------------------
// K5b: sequential chunk fix-up over NC chunks
// ---------------------------------------------------------------------------
__global__ __launch_bounds__(256) void k_scanB(const float* __restrict__ A_log,
                                               const float* __restrict__ dsum,
                                               const float* __restrict__ hend,
                                               float* __restrict__ hinit) {
    int idx = blockIdx.x * 256 + threadIdx.x;
    int n = idx & 15;
    int d = (idx >> 4) & 511;
    int b = idx >> 13;
    float Av = -__expf(A_log[d * 16 + n]);
    float h = 0.f;
    for (int c = 0; c < NC; c++) {
        size_t base = ((size_t)b * NC + c) * 512 + d;
        hinit[base * 16 + n] = h;
        float dsv = dsum[base];
        h = __expf(dsv * Av) * h + hend[base * 16 + n];
    }
}

// ---------------------------------------------------------------------------
// K5c: replay with hinit; emit y bf16: y[b][l][d] = (h.C + D*u)*silu(z)
// ---------------------------------------------------------------------------
__global__ __launch_bounds__(256) void k_scanC(const float* __restrict__ delta_t,
                                               const float* __restrict__ xdbl,
                                               const float* __restrict__ u_t,
                                               const float* __restrict__ xz_t,
                                               const float* __restrict__ A_log,
                                               const float* __restrict__ Dp,
                                               const float* __restrict__ hinit,
                                               ushort_t* __restrict__ y_bf) {
    __shared__ float Bt[CH][16];
    __shared__ float Ct[CH][16];
    const int t = threadIdx.x;
    const int d = blockIdx.y * 256 + t;
    const int b = blockIdx.z;
    const int c = blockIdx.x;
    const int l0 = c * CH;
    const size_t bl0 = (size_t)b * LL + l0;
    if (t < 128) {
        int l = t >> 2, n0 = (t & 3) * 4;
        *(float4*)&Bt[l][n0] = *(const float4*)(xdbl + (bl0 + l) * 48 + 16 + n0);
    } else {
        int t2 = t - 128;
        int l = t2 >> 2, n0 = (t2 & 3) * 4;
        *(float4*)&Ct[l][n0] = *(const float4*)(xdbl + (bl0 + l) * 48 + 32 + n0);
    }
    float Av[16];
    {
        const float4* Ar = (const float4*)(A_log + (size_t)d * 16);
#pragma unroll
        for (int q = 0; q < 4; q++) {
            float4 a = Ar[q];
            Av[q * 4 + 0] = -__expf(a.x);
            Av[q * 4 + 1] = -__expf(a.y);
            Av[q * 4 + 2] = -__expf(a.z);
            Av[q * 4 + 3] = -__expf(a.w);
        }
    }
    float h[16];
    {
        size_t base = ((size_t)b * NC + c) * 512 + d;
        const float4* hp = (const float4*)(hinit + base * 16);
#pragma unroll
        for (int q = 0; q < 4; q++) {
            float4 v = hp[q];
            h[q * 4 + 0] = v.x;
            h[q * 4 + 1] = v.y;
            h[q * 4 + 2] = v.z;
            h[q * 4 + 3] = v.w;
        }
    }
    __syncthreads();
    const float* dl = delta_t + bl0 * 512 + d;
    const float* ul = u_t + bl0 * 512 + d;
    const float* zl = xz_t + bl0 * 1024 + 512 + d;
    ushort_t* yl = y_bf + bl0 * 512 + d;
    const float Dv = Dp[d];
#pragma unroll 4
    for (int s = 0; s < CH; s++) {
        float de = dl[(size_t)s * 512];
        float uu = ul[(size_t)s * 512];
        float zz = zl[(size_t)s * 1024];
        float du = de * uu;
        float dot = 0.f;
#pragma unroll
        for (int n = 0; n < 16; n++) {
            float dA = __expf(de * Av[n]);
            h[n] = dA * h[n] + du * Bt[s][n];
            dot += h[n] * Ct[s][n];
        }
        float sig = 1.f / (1.f + __expf(-zz));
        yl[(size_t)s * 512] = f2bf((dot + Dv * uu) * (zz * sig));
    }
}

// ---------------------------------------------------------------------------
// K6: MFMA GEMM  out[b][o][l] = sum_d W_out[o][d]*y[b][l][d] + x[b][o][l]
// A-operand = y rows(l)... no: A = W_out rows(o)? D row = A-row.
// We need out[o][l] with col(lane&15)=l -> B-operand rows = l = y[l][d].
// A-operand = W_out[o][d]. Tile 64(o) x 128(l), 4 waves along l, BK=64.
// ---------------------------------------------------------------------------
__global__ __launch_bounds__(256) void k_gemm_out(const ushort_t* __restrict__ Wb,
                                                  const ushort_t* __restrict__ yb,
                                                  const float* __restrict__ x,
                                                  float* __restrict__ out) {
    __shared__ short As[64 * 64];
    __shared__ short Bs[128 * 64];
    const int b = blockIdx.z;
    const int l0 = blockIdx.x * 128;
    const int o0 = blockIdx.y * 64;
    const int t = threadIdx.x;
    const int lane = t & 63, wv = t >> 6;
    const ushort_t* ybb = yb + (size_t)b * LL * DI;
    f32x4 acc[4][2] = {};
    for (int k0 = 0; k0 < DI; k0 += 64) {
#pragma unroll
        for (int i = 0; i < 2; i++) {
            int ci = t + i * 256;
            int r = ci >> 3;
            int cb = (ci & 7) * 16;
            int pd = r * 128 + (cb ^ ((r & 7) << 4));
            *(float4*)((char*)As + pd) =
                *(const float4*)((const char*)(Wb + (size_t)(o0 + r) * DI + k0) + cb);
        }
#pragma unroll
        for (int i = 0; i < 4; i++) {
            int ci = t + i * 256;
            int r = ci >> 3;
            int cb = (ci & 7) * 16;
            int pd = r * 128 + (cb ^ ((r & 7) << 4));
            *(float4*)((char*)Bs + pd) =
                *(const float4*)((const char*)(ybb + (size_t)(l0 + r) * DI + k0) + cb);
        }
        __syncthreads();
#pragma unroll
        for (int kk = 0; kk < 2; kk++) {
            const int lcb = kk * 64 + (lane >> 4) * 16;
            bf16x8 af[4], bfr[2];
#pragma unroll
            for (int mi = 0; mi < 4; mi++) {
                int r = mi * 16 + (lane & 15);
                af[mi] = *(const bf16x8*)((const char*)As + r * 128 + (lcb ^ ((r & 7) << 4)));
            }
#pragma unroll
            for (int ni = 0; ni < 2; ni++) {
                int r = wv * 32 + ni * 16 + (lane & 15);
                bfr[ni] = *(const bf16x8*)((const char*)Bs + r * 128 + (lcb ^ ((r & 7) << 4)));
            }
#pragma unroll
            for (int mi = 0; mi < 4; mi++)
#pragma unroll
                for (int ni = 0; ni < 2; ni++)
                    acc[mi][ni] = __builtin_amdgcn_mfma_f32_16x16x32_bf16(
                        af[mi], bfr[ni], acc[mi][ni], 0, 0, 0);
        }
        __syncthreads();
    }
#pragma unroll
    for (int mi = 0; mi < 4; mi++) {
#pragma unroll
        for (int q = 0; q < 4; q++) {
            int o = o0 + mi * 16 + (lane >> 4) * 4 + q;
#pragma unroll
            for (int ni = 0; ni < 2; ni++) {
                int l = l0 + wv * 32 + ni * 16 + (lane & 15);
                size_t a = ((size_t)b * DM + o) * LL + l;
                out[a] = acc[mi][ni][q] + x[a];
            }
        }
    }
}

// ---------------------------------------------------------------------------
extern "C" void kernel_launch(void* const* d_in, const int* in_sizes, int n_in,
                              void* d_out, int out_size, void* d_ws, size_t ws_size,
                              hipStream_t stream) {
    const float* x = (const float*)d_in[0];
    const float* W_in = (const float*)d_in[1];
    const float* W_dw = (const float*)d_in[2];
    const float* b_dw = (const float*)d_in[3];
    const float* W_x = (const float*)d_in[4];
    const float* W_dt = (const float*)d_in[5];
    const float* b_dt = (const float*)d_in[6];
    const float* A_log = (const float*)d_in[7];
    const float* Dp = (const float*)d_in[8];
    const float* W_out = (const float*)d_in[9];
    float* out = (float*)d_out;

    float* ws = (float*)d_ws;
    float* xz_t = ws;                                   // B*L*1024
    float* u_t = xz_t + (size_t)BB * LL * 1024;         // B*L*512
    float* xdbl = u_t + (size_t)BB * LL * 512;          // B*L*48
    float* delta_t = xdbl + (size_t)BB * LL * 48;       // B*L*512
    float* yslot = delta_t + (size_t)BB * LL * 512;     // B*L*512 (multi-use)
    float* dsum = yslot + (size_t)BB * LL * 512;        // B*NC*512
    float* hinit = dsum + (size_t)BB * NC * 512;        // B*NC*512*16
    ushort_t* wbf_in = (ushort_t*)(hinit + (size_t)BB * NC * 512 * 16);  // 262144
    ushort_t* wbf_out = wbf_in + 2 * DI * DM;           // 131072

    // aliases (lifetime-disjoint):
    ushort_t* xt = (ushort_t*)delta_t;  // xt dead before k_delta writes
    float* hend = yslot;                // hend dead after scanB
    ushort_t* y_bf = (ushort_t*)yslot;  // written by scanC

    k_cvt4<<<(2 * DI * DM / 4 + 255) / 256, 256, 0, stream>>>(W_in, wbf_in,
                                                              2 * DI * DM / 4);
    k_cvt4<<<(DM * DI / 4 + 255) / 256, 256, 0, stream>>>(W_out, wbf_out,
                                                          DM * DI / 4);
    k_cvt_x<<<dim3(LL / 64, DM / 64, BB), 256, 0, stream>>>(x, xt);
    k_gemm_in<<<dim3(LL / 128, 1024 / 128, BB), 256, 0, stream>>>(xt, wbf_in, xz_t);
    k_conv<<<(BB * LL * DI) / 256, 256, 0, stream>>>(xz_t, W_dw, b_dw, u_t);
    k_xdbl<<<dim3(LL / 32, BB), 256, 0, stream>>>(u_t, W_x, xdbl);
    k_delta<<<BB * LL, 256, 0, stream>>>(xdbl, W_dt, b_dt, delta_t);
    k_scanA<<<dim3(NC, DI / 256, BB), 256, 0, stream>>>(delta_t, xdbl, u_t, A_log,
                                                        hend, dsum);
    k_scanB<<<(BB * DI * 16) / 256, 256, 0, stream>>>(A_log, dsum, hend, hinit);
    k_scanC<<<dim3(NC, DI / 256, BB), 256, 0, stream>>>(delta_t, xdbl, u_t, xz_t,
                                                        A_log, Dp, hinit, y_bf);
    k_gemm_out<<<dim3(LL / 128, DM / 64, BB), 256, 0, stream>>>(wbf_out, y_bf, x, out);
}

// Round 4
// 134.833 us; speedup vs baseline: 2.5163x; 1.1582x over previous
//
#include <hip/hip_runtime.h>
#include <math.h>

#define DM 256
#define DI 512
#define BB 4
#define LL 2048
#define NC 64
#define CH (LL / NC)  // 32

typedef short bf16x8 __attribute__((ext_vector_type(8)));
typedef float f32x4 __attribute__((ext_vector_type(4)));
typedef unsigned short u16;

__device__ inline u16 f2bf(float f) {
    union { float f; unsigned u; } v;
    v.f = f;
    return (u16)((v.u + 0x7FFF + ((v.u >> 16) & 1)) >> 16);
}
__device__ inline float bf2f(u16 h) {
    union { unsigned u; float f; } v;
    v.u = ((unsigned)h) << 16;
    return v.f;
}

// ---------------------------------------------------------------------------
// K0a: fp32 -> bf16 convert (4/thread)
// ---------------------------------------------------------------------------
__global__ __launch_bounds__(256) void k_cvt4(const float* __restrict__ s,
                                              u16* __restrict__ d, int n4) {
    int i = blockIdx.x * 256 + threadIdx.x;
    if (i >= n4) return;
    float4 v = ((const float4*)s)[i];
    unsigned o0 = (unsigned)f2bf(v.x) | ((unsigned)f2bf(v.y) << 16);
    unsigned o1 = (unsigned)f2bf(v.z) | ((unsigned)f2bf(v.w) << 16);
    ((uint2*)d)[i] = make_uint2(o0, o1);
}

// ---------------------------------------------------------------------------
// K0b: x[b][m][l] fp32 -> xt[b][l][m] bf16
// ---------------------------------------------------------------------------
__global__ __launch_bounds__(256) void k_cvt_x(const float* __restrict__ x,
                                               u16* __restrict__ xt) {
    __shared__ float tile[64][65];
    const int b = blockIdx.z;
    const int m0 = blockIdx.y * 64;
    const int l0 = blockIdx.x * 64;
    const float* xb = x + ((size_t)b * DM + m0) * LL + l0;
    const int t = threadIdx.x;
#pragma unroll
    for (int i = 0; i < 16; i++) {
        int idx = t + i * 256;
        int r = idx >> 6, c = idx & 63;
        tile[r][c] = xb[(size_t)r * LL + c];
    }
    __syncthreads();
    u16* ob = xt + ((size_t)b * LL + l0) * DM + m0;
#pragma unroll
    for (int i = 0; i < 16; i++) {
        int idx = t + i * 256;
        int r = idx >> 6, c = idx & 63;
        ob[(size_t)r * DM + c] = f2bf(tile[c][r]);
    }
}

// ---------------------------------------------------------------------------
// K1: MFMA GEMM  xz[b][l][c] (bf16) = sum_m xt[b][l][m] * W_in[c][m]
// 128x128 tile, BK=64, 4 waves 2x2, 16x16x32 bf16 MFMA, T2 XOR swizzle.
// ---------------------------------------------------------------------------
__global__ __launch_bounds__(256) void k_gemm_in(const u16* __restrict__ xt,
                                                 const u16* __restrict__ Wb,
                                                 u16* __restrict__ xz) {
    __shared__ short As[128 * 64];
    __shared__ short Bs[128 * 64];
    const int b = blockIdx.z;
    const int l0 = blockIdx.x * 128;
    const int c0 = blockIdx.y * 128;
    const int t = threadIdx.x;
    const int lane = t & 63, wv = t >> 6;
    const int wr = wv >> 1, wc = wv & 1;
    const u16* xb = xt + (size_t)b * LL * DM;
    f32x4 acc[4][4] = {};
    for (int k0 = 0; k0 < DM; k0 += 64) {
#pragma unroll
        for (int i = 0; i < 4; i++) {
            int ci = t + i * 256;
            int r = ci >> 3;
            int cb = (ci & 7) * 16;
            int pd = r * 128 + (cb ^ ((r & 7) << 4));
            *(float4*)((char*)As + pd) =
                *(const float4*)((const char*)(xb + (size_t)(l0 + r) * DM + k0) + cb);
            *(float4*)((char*)Bs + pd) =
                *(const float4*)((const char*)(Wb + (size_t)(c0 + r) * DM + k0) + cb);
        }
        __syncthreads();
#pragma unroll
        for (int kk = 0; kk < 2; kk++) {
            const int lcb = kk * 64 + (lane >> 4) * 16;
            bf16x8 af[4], bfr[4];
#pragma unroll
            for (int mi = 0; mi < 4; mi++) {
                int r = wr * 64 + mi * 16 + (lane & 15);
                af[mi] = *(const bf16x8*)((const char*)As + r * 128 + (lcb ^ ((r & 7) << 4)));
            }
#pragma unroll
            for (int ni = 0; ni < 4; ni++) {
                int r = wc * 64 + ni * 16 + (lane & 15);
                bfr[ni] = *(const bf16x8*)((const char*)Bs + r * 128 + (lcb ^ ((r & 7) << 4)));
            }
#pragma unroll
            for (int mi = 0; mi < 4; mi++)
#pragma unroll
                for (int ni = 0; ni < 4; ni++)
                    acc[mi][ni] = __builtin_amdgcn_mfma_f32_16x16x32_bf16(
                        af[mi], bfr[ni], acc[mi][ni], 0, 0, 0);
        }
        __syncthreads();
    }
    u16* ob = xz + (size_t)b * LL * 1024;
#pragma unroll
    for (int mi = 0; mi < 4; mi++) {
#pragma unroll
        for (int q = 0; q < 4; q++) {
            int l = l0 + wr * 64 + mi * 16 + (lane >> 4) * 4 + q;
#pragma unroll
            for (int ni = 0; ni < 4; ni++) {
                int c = c0 + wc * 64 + ni * 16 + (lane & 15);
                ob[(size_t)l * 1024 + c] = f2bf(acc[mi][ni][q]);
            }
        }
    }
}

// ---------------------------------------------------------------------------
// K2: FUSED conv(k=3)+silu -> u ; xdbl = Wx*u ; delta = softplus(Wdt*dt+b)
// block = (b, 16 l's). 8 k-chunks of 64 d. LDS: lu[16][65], lwx[48][65].
// ---------------------------------------------------------------------------
__global__ __launch_bounds__(256) void k_fused(const u16* __restrict__ xz,
                                               const float* __restrict__ Wdw,
                                               const float* __restrict__ bdw,
                                               const float* __restrict__ Wx,
                                               const float* __restrict__ Wdt,
                                               const float* __restrict__ bdt,
                                               u16* __restrict__ u_bf,
                                               float* __restrict__ xdbl,
                                               u16* __restrict__ delta_bf) {
    __shared__ float lu[16][65];
    __shared__ float lwx[48][65];
    __shared__ float xd[16][17];
    const int b = blockIdx.y;
    const int l0 = blockIdx.x * 16;
    const int t = threadIdx.x;
    const int dl = t & 63;
    const int lr = t >> 6;
    const int lq = t & 15, cg = t >> 4;
    const u16* xzb = xz + (size_t)b * LL * 1024;
    float acc[3] = {};
    for (int k0 = 0; k0 < DI; k0 += 64) {
        if (k0) __syncthreads();
        int d = k0 + dl;
        float w0 = Wdw[d * 3], w1 = Wdw[d * 3 + 1], w2 = Wdw[d * 3 + 2];
        float bb = bdw[d];
#pragma unroll
        for (int i = 0; i < 4; i++) {
            int ll = lr + i * 4;
            int gl = l0 + ll;
            float v = bb + w1 * bf2f(xzb[(size_t)gl * 1024 + d]);
            if (gl > 0) v += w0 * bf2f(xzb[(size_t)(gl - 1) * 1024 + d]);
            if (gl < LL - 1) v += w2 * bf2f(xzb[(size_t)(gl + 1) * 1024 + d]);
            float uu = v / (1.f + __expf(-v));
            lu[ll][dl] = uu;
            u_bf[((size_t)b * LL + gl) * DI + d] = f2bf(uu);
        }
#pragma unroll
        for (int i = 0; i < 12; i++) {
            int idx = t + i * 256;
            int r = idx >> 6, cc = idx & 63;
            lwx[r][cc] = Wx[(size_t)r * DI + k0 + cc];
        }
        __syncthreads();
#pragma unroll
        for (int kk = 0; kk < 64; kk++) {
            float uv = lu[lq][kk];
#pragma unroll
            for (int i = 0; i < 3; i++) acc[i] += lwx[cg * 3 + i][kk] * uv;
        }
    }
    {
        int gl = l0 + lq;
#pragma unroll
        for (int i = 0; i < 3; i++) {
            int c = cg * 3 + i;
            xdbl[((size_t)b * LL + gl) * 48 + c] = acc[i];
            if (c < 16) xd[lq][c] = acc[i];
        }
    }
    __syncthreads();
#pragma unroll
    for (int h = 0; h < 2; h++) {
        int d = t + h * 256;
        float wr[16];
        const float4* wp = (const float4*)(Wdt + (size_t)d * 16);
#pragma unroll
        for (int q = 0; q < 4; q++) {
            float4 w = wp[q];
            wr[q * 4] = w.x; wr[q * 4 + 1] = w.y; wr[q * 4 + 2] = w.z; wr[q * 4 + 3] = w.w;
        }
        float bv = bdt[d];
        for (int ll = 0; ll < 16; ll++) {
            float a = bv;
#pragma unroll
            for (int q = 0; q < 16; q++) a += wr[q] * xd[ll][q];
            float sp = fmaxf(a, 0.f) + log1pf(__expf(-fabsf(a)));
            delta_bf[((size_t)b * LL + l0 + ll) * DI + d] = f2bf(sp);
        }
    }
}

// ---------------------------------------------------------------------------
// K3a: per-chunk local scan (bf16 in, h[16] regs, guarded exp-power trick)
// ---------------------------------------------------------------------------
__global__ __launch_bounds__(256) void k_scanA(const u16* __restrict__ delta_bf,
                                               const float* __restrict__ xdbl,
                                               const u16* __restrict__ u_bf,
                                               const float* __restrict__ A_log,
                                               u16* __restrict__ hend,
                                               float* __restrict__ dsum) {
    __shared__ float Bt[CH][16];
    const int t = threadIdx.x;
    const int d = blockIdx.y * 256 + t;
    const int b = blockIdx.z;
    const int c = blockIdx.x;
    const int l0 = c * CH;
    const size_t bl0 = (size_t)b * LL + l0;
    if (t < CH * 4) {
        int l = t >> 2, n0 = (t & 3) * 4;
        *(float4*)&Bt[l][n0] = *(const float4*)(xdbl + (bl0 + l) * 48 + 16 + n0);
    }
    float Av[16];
    bool fast = true;
    {
        const float4* Ar = (const float4*)(A_log + (size_t)d * 16);
#pragma unroll
        for (int q = 0; q < 4; q++) {
            float4 a = Ar[q];
            Av[q * 4] = -__expf(a.x); Av[q * 4 + 1] = -__expf(a.y);
            Av[q * 4 + 2] = -__expf(a.z); Av[q * 4 + 3] = -__expf(a.w);
        }
#pragma unroll
        for (int n = 0; n < 16; n++)
            fast = fast && (fabsf(Av[n] + (float)(n + 1)) < 1e-4f * (n + 1));
    }
    __syncthreads();
    const u16* dl = delta_bf + bl0 * DI + d;
    const u16* ul = u_bf + bl0 * DI + d;
    float h[16] = {};
    float ds = 0.f;
#pragma unroll 2
    for (int s = 0; s < CH; s++) {
        float de = bf2f(dl[(size_t)s * DI]);
        float uu = bf2f(ul[(size_t)s * DI]);
        float du = de * uu;
        ds += de;
        float pw[16];
        if (fast) {
            float p1 = __expf(-de);
            float p2 = p1 * p1, p4 = p2 * p2, p8 = p4 * p4;
            pw[0] = p1; pw[1] = p2; pw[2] = p2 * p1; pw[3] = p4;
            pw[4] = p4 * p1; pw[5] = p4 * p2; pw[6] = p4 * pw[2]; pw[7] = p8;
            pw[8] = p8 * p1; pw[9] = p8 * p2; pw[10] = p8 * pw[2]; pw[11] = p8 * p4;
            pw[12] = p8 * pw[4]; pw[13] = p8 * pw[5]; pw[14] = p8 * pw[6]; pw[15] = p8 * p8;
        } else {
#pragma unroll
            for (int n = 0; n < 16; n++) pw[n] = __expf(de * Av[n]);
        }
#pragma unroll
        for (int q = 0; q < 4; q++) {
            f32x4 Bv = *(const f32x4*)&Bt[s][q * 4];
#pragma unroll
            for (int j = 0; j < 4; j++) {
                int n = q * 4 + j;
                h[n] = pw[n] * h[n] + du * Bv[j];
            }
        }
    }
    size_t base = ((size_t)b * NC + c) * DI + d;
#pragma unroll
    for (int n = 0; n < 16; n++) hend[base * 16 + n] = f2bf(h[n]);
    dsum[base] = ds;
}

// ---------------------------------------------------------------------------
// K3b: sequential chunk fix-up (bf16 hend/hinit)
// ---------------------------------------------------------------------------
__global__ __launch_bounds__(256) void k_scanB(const float* __restrict__ A_log,
                                               const float* __restrict__ dsum,
                                               const u16* __restrict__ hend,
                                               u16* __restrict__ hinit) {
    int idx = blockIdx.x * 256 + threadIdx.x;
    int n = idx & 15;
    int d = (idx >> 4) & 511;
    int b = idx >> 13;
    float Av = -__expf(A_log[d * 16 + n]);
    float h = 0.f;
    for (int c = 0; c < NC; c++) {
        size_t base = ((size_t)b * NC + c) * DI + d;
        hinit[base * 16 + n] = f2bf(h);
        h = __expf(dsum[base] * Av) * h + bf2f(hend[base * 16 + n]);
    }
}

// ---------------------------------------------------------------------------
// K3c: replay; y[b][l][d] (bf16) = (h.C + D*u)*silu(z)
// ---------------------------------------------------------------------------
__global__ __launch_bounds__(256) void k_scanC(const u16* __restrict__ delta_bf,
                                               const float* __restrict__ xdbl,
                                               const u16* __restrict__ u_bf,
                                               const u16* __restrict__ xz,
                                               const float* __restrict__ A_log,
                                               const float* __restrict__ Dp,
                                               const u16* __restrict__ hinit,
                                               u16* __restrict__ y_bf) {
    __shared__ float Bt[CH][16];
    __shared__ float Ct[CH][16];
    const int t = threadIdx.x;
    const int d = blockIdx.y * 256 + t;
    const int b = blockIdx.z;
    const int c = blockIdx.x;
    const int l0 = c * CH;
    const size_t bl0 = (size_t)b * LL + l0;
    if (t < 128) {
        int l = t >> 2, n0 = (t & 3) * 4;
        *(float4*)&Bt[l][n0] = *(const float4*)(xdbl + (bl0 + l) * 48 + 16 + n0);
    } else {
        int t2 = t - 128;
        int l = t2 >> 2, n0 = (t2 & 3) * 4;
        *(float4*)&Ct[l][n0] = *(const float4*)(xdbl + (bl0 + l) * 48 + 32 + n0);
    }
    float Av[16];
    bool fast = true;
    {
        const float4* Ar = (const float4*)(A_log + (size_t)d * 16);
#pragma unroll
        for (int q = 0; q < 4; q++) {
            float4 a = Ar[q];
            Av[q * 4] = -__expf(a.x); Av[q * 4 + 1] = -__expf(a.y);
            Av[q * 4 + 2] = -__expf(a.z); Av[q * 4 + 3] = -__expf(a.w);
        }
#pragma unroll
        for (int n = 0; n < 16; n++)
            fast = fast && (fabsf(Av[n] + (float)(n + 1)) < 1e-4f * (n + 1));
    }
    float h[16];
    {
        size_t base = ((size_t)b * NC + c) * DI + d;
#pragma unroll
        for (int n = 0; n < 16; n++) h[n] = bf2f(hinit[base * 16 + n]);
    }
    __syncthreads();
    const u16* dl = delta_bf + bl0 * DI + d;
    const u16* ul = u_bf + bl0 * DI + d;
    const u16* zl = xz + bl0 * 1024 + 512 + d;
    u16* yl = y_bf + bl0 * DI + d;
    const float Dv = Dp[d];
#pragma unroll 2
    for (int s = 0; s < CH; s++) {
        float de = bf2f(dl[(size_t)s * DI]);
        float uu = bf2f(ul[(size_t)s * DI]);
        float zz = bf2f(zl[(size_t)s * 1024]);
        float du = de * uu;
        float pw[16];
        if (fast) {
            float p1 = __expf(-de);
            float p2 = p1 * p1, p4 = p2 * p2, p8 = p4 * p4;
            pw[0] = p1; pw[1] = p2; pw[2] = p2 * p1; pw[3] = p4;
            pw[4] = p4 * p1; pw[5] = p4 * p2; pw[6] = p4 * pw[2]; pw[7] = p8;
            pw[8] = p8 * p1; pw[9] = p8 * p2; pw[10] = p8 * pw[2]; pw[11] = p8 * p4;
            pw[12] = p8 * pw[4]; pw[13] = p8 * pw[5]; pw[14] = p8 * pw[6]; pw[15] = p8 * p8;
        } else {
#pragma unroll
            for (int n = 0; n < 16; n++) pw[n] = __expf(de * Av[n]);
        }
        float dot = 0.f;
#pragma unroll
        for (int q = 0; q < 4; q++) {
            f32x4 Bv = *(const f32x4*)&Bt[s][q * 4];
            f32x4 Cv = *(const f32x4*)&Ct[s][q * 4];
#pragma unroll
            for (int j = 0; j < 4; j++) {
                int n = q * 4 + j;
                h[n] = pw[n] * h[n] + du * Bv[j];
                dot += h[n] * Cv[j];
            }
        }
        float sig = 1.f / (1.f + __expf(-zz));
        yl[(size_t)s * DI] = f2bf((dot + Dv * uu) * (zz * sig));
    }
}

// ---------------------------------------------------------------------------
// K4: MFMA GEMM  out[b][o][l] = sum_d W_out[o][d]*y[b][l][d] + x[b][o][l]
// ---------------------------------------------------------------------------
__global__ __launch_bounds__(256) void k_gemm_out(const u16* __restrict__ Wb,
                                                  const u16* __restrict__ yb,
                                                  const float* __restrict__ x,
                                                  float* __restrict__ out) {
    __shared__ short As[64 * 64];
    __shared__ short Bs[128 * 64];
    const int b = blockIdx.z;
    const int l0 = blockIdx.x * 128;
    const int o0 = blockIdx.y * 64;
    const int t = threadIdx.x;
    const int lane = t & 63, wv = t >> 6;
    const u16* ybb = yb + (size_t)b * LL * DI;
    f32x4 acc[4][2] = {};
    for (int k0 = 0; k0 < DI; k0 += 64) {
#pragma unroll
        for (int i = 0; i < 2; i++) {
            int ci = t + i * 256;
            int r = ci >> 3;
            int cb = (ci & 7) * 16;
            int pd = r * 128 + (cb ^ ((r & 7) << 4));
            *(float4*)((char*)As + pd) =
                *(const float4*)((const char*)(Wb + (size_t)(o0 + r) * DI + k0) + cb);
        }
#pragma unroll
        for (int i = 0; i < 4; i++) {
            int ci = t + i * 256;
            int r = ci >> 3;
            int cb = (ci & 7) * 16;
            int pd = r * 128 + (cb ^ ((r & 7) << 4));
            *(float4*)((char*)Bs + pd) =
                *(const float4*)((const char*)(ybb + (size_t)(l0 + r) * DI + k0) + cb);
        }
        __syncthreads();
#pragma unroll
        for (int kk = 0; kk < 2; kk++) {
            const int lcb = kk * 64 + (lane >> 4) * 16;
            bf16x8 af[4], bfr[2];
#pragma unroll
            for (int mi = 0; mi < 4; mi++) {
                int r = mi * 16 + (lane & 15);
                af[mi] = *(const bf16x8*)((const char*)As + r * 128 + (lcb ^ ((r & 7) << 4)));
            }
#pragma unroll
            for (int ni = 0; ni < 2; ni++) {
                int r = wv * 32 + ni * 16 + (lane & 15);
                bfr[ni] = *(const bf16x8*)((const char*)Bs + r * 128 + (lcb ^ ((r & 7) << 4)));
            }
#pragma unroll
            for (int mi = 0; mi < 4; mi++)
#pragma unroll
                for (int ni = 0; ni < 2; ni++)
                    acc[mi][ni] = __builtin_amdgcn_mfma_f32_16x16x32_bf16(
                        af[mi], bfr[ni], acc[mi][ni], 0, 0, 0);
        }
        __syncthreads();
    }
#pragma unroll
    for (int mi = 0; mi < 4; mi++) {
#pragma unroll
        for (int q = 0; q < 4; q++) {
            int o = o0 + mi * 16 + (lane >> 4) * 4 + q;
#pragma unroll
            for (int ni = 0; ni < 2; ni++) {
                int l = l0 + wv * 32 + ni * 16 + (lane & 15);
                size_t a = ((size_t)b * DM + o) * LL + l;
                out[a] = acc[mi][ni][q] + x[a];
            }
        }
    }
}

// ---------------------------------------------------------------------------
extern "C" void kernel_launch(void* const* d_in, const int* in_sizes, int n_in,
                              void* d_out, int out_size, void* d_ws, size_t ws_size,
                              hipStream_t stream) {
    const float* x = (const float*)d_in[0];
    const float* W_in = (const float*)d_in[1];
    const float* W_dw = (const float*)d_in[2];
    const float* b_dw = (const float*)d_in[3];
    const float* W_x = (const float*)d_in[4];
    const float* W_dt = (const float*)d_in[5];
    const float* b_dt = (const float*)d_in[6];
    const float* A_log = (const float*)d_in[7];
    const float* Dp = (const float*)d_in[8];
    const float* W_out = (const float*)d_in[9];
    float* out = (float*)d_out;

    char* p = (char*)d_ws;
    u16* xz_bf = (u16*)p;      p += (size_t)BB * LL * 1024 * 2;   // 16.8 MB
    u16* u_bf = (u16*)p;       p += (size_t)BB * LL * DI * 2;     // 8.4 MB
    u16* delta_bf = (u16*)p;   p += (size_t)BB * LL * DI * 2;     // 8.4 MB
    float* xdbl = (float*)p;   p += (size_t)BB * LL * 48 * 4;     // 1.6 MB
    u16* y_bf = (u16*)p;       p += (size_t)BB * LL * DI * 2;     // 8.4 MB
    float* dsum = (float*)p;   p += (size_t)BB * NC * DI * 4;     // 0.5 MB
    u16* hinit = (u16*)p;      p += (size_t)BB * NC * DI * 16 * 2; // 4.2 MB
    u16* wbf_in = (u16*)p;     p += (size_t)2 * DI * DM * 2;
    u16* wbf_out = (u16*)p;    p += (size_t)DM * DI * 2;
    // aliases (lifetime-disjoint):
    u16* xt = delta_bf;  // xt dead (after gemm_in) before k_fused writes delta
    u16* hend = y_bf;    // hend dead (after scanB) before scanC writes y

    k_cvt4<<<(2 * DI * DM / 4 + 255) / 256, 256, 0, stream>>>(W_in, wbf_in,
                                                              2 * DI * DM / 4);
    k_cvt4<<<(DM * DI / 4 + 255) / 256, 256, 0, stream>>>(W_out, wbf_out,
                                                          DM * DI / 4);
    k_cvt_x<<<dim3(LL / 64, DM / 64, BB), 256, 0, stream>>>(x, xt);
    k_gemm_in<<<dim3(LL / 128, 1024 / 128, BB), 256, 0, stream>>>(xt, wbf_in, xz_bf);
    k_fused<<<dim3(LL / 16, BB), 256, 0, stream>>>(xz_bf, W_dw, b_dw, W_x, W_dt,
                                                   b_dt, u_bf, xdbl, delta_bf);
    k_scanA<<<dim3(NC, DI / 256, BB), 256, 0, stream>>>(delta_bf, xdbl, u_bf, A_log,
                                                        hend, dsum);
    k_scanB<<<(BB * DI * 16) / 256, 256, 0, stream>>>(A_log, dsum, hend, hinit);
    k_scanC<<<dim3(NC, DI / 256, BB), 256, 0, stream>>>(delta_bf, xdbl, u_bf, xz_bf,
                                                        A_log, Dp, hinit, y_bf);
    k_gemm_out<<<dim3(LL / 128, DM / 64, BB), 256, 0, stream>>>(wbf_out, y_bf, x, out);
}

// Round 5
// 116.029 us; speedup vs baseline: 2.9241x; 1.1621x over previous
//
#include <hip/hip_runtime.h>
#include <math.h>

#define DM 256
#define DI 512
#define BB 4
#define LL 2048
#define NC 64
#define CH (LL / NC)  // 32

typedef short bf16x8 __attribute__((ext_vector_type(8)));
typedef float f32x4 __attribute__((ext_vector_type(4)));
typedef unsigned short u16;

__device__ inline u16 f2bf(float f) {
    union { float f; unsigned u; } v;
    v.f = f;
    return (u16)((v.u + 0x7FFF + ((v.u >> 16) & 1)) >> 16);
}
__device__ inline float bf2f(u16 h) {
    union { unsigned u; float f; } v;
    v.u = ((unsigned)h) << 16;
    return v.f;
}

// ---------------------------------------------------------------------------
// K0a: fp32 -> bf16 convert (4/thread)
// ---------------------------------------------------------------------------
__global__ __launch_bounds__(256) void k_cvt4(const float* __restrict__ s,
                                              u16* __restrict__ d, int n4) {
    int i = blockIdx.x * 256 + threadIdx.x;
    if (i >= n4) return;
    float4 v = ((const float4*)s)[i];
    unsigned o0 = (unsigned)f2bf(v.x) | ((unsigned)f2bf(v.y) << 16);
    unsigned o1 = (unsigned)f2bf(v.z) | ((unsigned)f2bf(v.w) << 16);
    ((uint2*)d)[i] = make_uint2(o0, o1);
}

// ---------------------------------------------------------------------------
// K0b: x[b][m][l] fp32 -> xt[b][l][m] bf16
// ---------------------------------------------------------------------------
__global__ __launch_bounds__(256) void k_cvt_x(const float* __restrict__ x,
                                               u16* __restrict__ xt) {
    __shared__ float tile[64][65];
    const int b = blockIdx.z;
    const int m0 = blockIdx.y * 64;
    const int l0 = blockIdx.x * 64;
    const float* xb = x + ((size_t)b * DM + m0) * LL + l0;
    const int t = threadIdx.x;
#pragma unroll
    for (int i = 0; i < 16; i++) {
        int idx = t + i * 256;
        int r = idx >> 6, c = idx & 63;
        tile[r][c] = xb[(size_t)r * LL + c];
    }
    __syncthreads();
    u16* ob = xt + ((size_t)b * LL + l0) * DM + m0;
#pragma unroll
    for (int i = 0; i < 16; i++) {
        int idx = t + i * 256;
        int r = idx >> 6, c = idx & 63;
        ob[(size_t)r * DM + c] = f2bf(tile[c][r]);
    }
}

// ---------------------------------------------------------------------------
// K1: MFMA GEMM  xz[b][l][c] (bf16) = sum_m xt[b][l][m] * W_in[c][m]
// 128x128 tile, BK=64, 4 waves 2x2, 16x16x32 bf16 MFMA, T2 XOR swizzle.
// ---------------------------------------------------------------------------
__global__ __launch_bounds__(256) void k_gemm_in(const u16* __restrict__ xt,
                                                 const u16* __restrict__ Wb,
                                                 u16* __restrict__ xz) {
    __shared__ short As[128 * 64];
    __shared__ short Bs[128 * 64];
    const int b = blockIdx.z;
    const int l0 = blockIdx.x * 128;
    const int c0 = blockIdx.y * 128;
    const int t = threadIdx.x;
    const int lane = t & 63, wv = t >> 6;
    const int wr = wv >> 1, wc = wv & 1;
    const u16* xb = xt + (size_t)b * LL * DM;
    f32x4 acc[4][4] = {};
    for (int k0 = 0; k0 < DM; k0 += 64) {
#pragma unroll
        for (int i = 0; i < 4; i++) {
            int ci = t + i * 256;
            int r = ci >> 3;
            int cb = (ci & 7) * 16;
            int pd = r * 128 + (cb ^ ((r & 7) << 4));
            *(float4*)((char*)As + pd) =
                *(const float4*)((const char*)(xb + (size_t)(l0 + r) * DM + k0) + cb);
            *(float4*)((char*)Bs + pd) =
                *(const float4*)((const char*)(Wb + (size_t)(c0 + r) * DM + k0) + cb);
        }
        __syncthreads();
#pragma unroll
        for (int kk = 0; kk < 2; kk++) {
            const int lcb = kk * 64 + (lane >> 4) * 16;
            bf16x8 af[4], bfr[4];
#pragma unroll
            for (int mi = 0; mi < 4; mi++) {
                int r = wr * 64 + mi * 16 + (lane & 15);
                af[mi] = *(const bf16x8*)((const char*)As + r * 128 + (lcb ^ ((r & 7) << 4)));
            }
#pragma unroll
            for (int ni = 0; ni < 4; ni++) {
                int r = wc * 64 + ni * 16 + (lane & 15);
                bfr[ni] = *(const bf16x8*)((const char*)Bs + r * 128 + (lcb ^ ((r & 7) << 4)));
            }
#pragma unroll
            for (int mi = 0; mi < 4; mi++)
#pragma unroll
                for (int ni = 0; ni < 4; ni++)
                    acc[mi][ni] = __builtin_amdgcn_mfma_f32_16x16x32_bf16(
                        af[mi], bfr[ni], acc[mi][ni], 0, 0, 0);
        }
        __syncthreads();
    }
    u16* ob = xz + (size_t)b * LL * 1024;
#pragma unroll
    for (int mi = 0; mi < 4; mi++) {
#pragma unroll
        for (int q = 0; q < 4; q++) {
            int l = l0 + wr * 64 + mi * 16 + (lane >> 4) * 4 + q;
#pragma unroll
            for (int ni = 0; ni < 4; ni++) {
                int c = c0 + wc * 64 + ni * 16 + (lane & 15);
                ob[(size_t)l * 1024 + c] = f2bf(acc[mi][ni][q]);
            }
        }
    }
}

// ---------------------------------------------------------------------------
// K2a: depthwise conv k=3 + bias + silu, bf16->bf16, 8 d's/thread
// ---------------------------------------------------------------------------
__global__ __launch_bounds__(256) void k_conv(const u16* __restrict__ xz,
                                              const float* __restrict__ Wdw,
                                              const float* __restrict__ bdw,
                                              u16* __restrict__ u_bf) {
    int idx = blockIdx.x * 256 + threadIdx.x;  // over BB*LL*64 groups of 8
    int g = idx & 63;
    int l = (idx >> 6) & (LL - 1);
    int b = idx >> 17;
    int d0 = g * 8;
    const u16* row = xz + ((size_t)b * LL + l) * 1024 + d0;
    ushort4 c0a = *(const ushort4*)(row);
    ushort4 c0b = *(const ushort4*)(row + 4);
    ushort4 cma, cmb, cpa, cpb;
    if (l > 0) { cma = *(const ushort4*)(row - 1024); cmb = *(const ushort4*)(row - 1020); }
    else { cma = make_ushort4(0,0,0,0); cmb = cma; }
    if (l < LL - 1) { cpa = *(const ushort4*)(row + 1024); cpb = *(const ushort4*)(row + 1028); }
    else { cpa = make_ushort4(0,0,0,0); cpb = cpa; }
    u16 xm[8] = {cma.x, cma.y, cma.z, cma.w, cmb.x, cmb.y, cmb.z, cmb.w};
    u16 x0[8] = {c0a.x, c0a.y, c0a.z, c0a.w, c0b.x, c0b.y, c0b.z, c0b.w};
    u16 xp[8] = {cpa.x, cpa.y, cpa.z, cpa.w, cpb.x, cpb.y, cpb.z, cpb.w};
    u16 out[8];
#pragma unroll
    for (int j = 0; j < 8; j++) {
        int d = d0 + j;
        float v = bdw[d] + Wdw[d * 3] * bf2f(xm[j]) + Wdw[d * 3 + 1] * bf2f(x0[j]) +
                  Wdw[d * 3 + 2] * bf2f(xp[j]);
        float uu = v / (1.f + __expf(-v));
        out[j] = f2bf(uu);
    }
    u16* ou = u_bf + ((size_t)b * LL + l) * DI + d0;
    *(ushort4*)(ou) = make_ushort4(out[0], out[1], out[2], out[3]);
    *(ushort4*)(ou + 4) = make_ushort4(out[4], out[5], out[6], out[7]);
}

// ---------------------------------------------------------------------------
// K2b: MFMA GEMM  xdbl[bl][c] = sum_d u[bl][d] * Wx[c][d]  (M=8192,N=48,K=512)
// 64-row M-tile, 4 waves each 16 l's x 48 c, BK=64, XOR swizzle.
// ---------------------------------------------------------------------------
__global__ __launch_bounds__(256) void k_xdbl(const u16* __restrict__ u_bf,
                                              const u16* __restrict__ Wxb,
                                              float* __restrict__ xdbl) {
    __shared__ short Us[64 * 64];
    __shared__ short Ws[48 * 64];
    const int bl0 = blockIdx.x * 64;
    const int t = threadIdx.x;
    const int lane = t & 63, wv = t >> 6;
    f32x4 acc[3] = {};
    for (int k0 = 0; k0 < DI; k0 += 64) {
#pragma unroll
        for (int i = 0; i < 2; i++) {
            int ci = t + i * 256;
            int r = ci >> 3;
            int cb = (ci & 7) * 16;
            int pd = r * 128 + (cb ^ ((r & 7) << 4));
            *(float4*)((char*)Us + pd) =
                *(const float4*)((const char*)(u_bf + (size_t)(bl0 + r) * DI + k0) + cb);
            if (ci < 384)
                *(float4*)((char*)Ws + pd) =
                    *(const float4*)((const char*)(Wxb + (size_t)r * DI + k0) + cb);
        }
        __syncthreads();
#pragma unroll
        for (int kk = 0; kk < 2; kk++) {
            const int lcb = kk * 64 + (lane >> 4) * 16;
            int ra = wv * 16 + (lane & 15);
            bf16x8 af = *(const bf16x8*)((const char*)Us + ra * 128 + (lcb ^ ((ra & 7) << 4)));
#pragma unroll
            for (int ni = 0; ni < 3; ni++) {
                int r = ni * 16 + (lane & 15);
                bf16x8 bfr = *(const bf16x8*)((const char*)Ws + r * 128 + (lcb ^ ((r & 7) << 4)));
                acc[ni] = __builtin_amdgcn_mfma_f32_16x16x32_bf16(af, bfr, acc[ni], 0, 0, 0);
            }
        }
        __syncthreads();
    }
#pragma unroll
    for (int ni = 0; ni < 3; ni++) {
#pragma unroll
        for (int q = 0; q < 4; q++) {
            int l = bl0 + wv * 16 + (lane >> 4) * 4 + q;
            int c = ni * 16 + (lane & 15);
            xdbl[(size_t)l * 48 + c] = acc[ni][q];
        }
    }
}

// ---------------------------------------------------------------------------
// K2c: delta[bl][d] = softplus(bdt[d] + Wdt[d] . xdbl[bl][0:16]) -> bf16
// block = 16 l's, 256 threads, 2 d's x 16 l each
// ---------------------------------------------------------------------------
__global__ __launch_bounds__(256) void k_delta(const float* __restrict__ xdbl,
                                               const float* __restrict__ Wdt,
                                               const float* __restrict__ bdt,
                                               u16* __restrict__ delta_bf) {
    __shared__ float xd[16][17];
    const int bl0 = blockIdx.x * 16;
    const int t = threadIdx.x;
    {
        int l = t >> 4, r = t & 15;
        xd[l][r] = xdbl[(size_t)(bl0 + l) * 48 + r];
    }
    __syncthreads();
#pragma unroll
    for (int h = 0; h < 2; h++) {
        int d = t + h * 256;
        float wr[16];
        const float4* wp = (const float4*)(Wdt + (size_t)d * 16);
#pragma unroll
        for (int q = 0; q < 4; q++) {
            float4 w = wp[q];
            wr[q * 4] = w.x; wr[q * 4 + 1] = w.y; wr[q * 4 + 2] = w.z; wr[q * 4 + 3] = w.w;
        }
        float bv = bdt[d];
#pragma unroll 4
        for (int ll = 0; ll < 16; ll++) {
            float a = bv;
#pragma unroll
            for (int q = 0; q < 16; q++) a += wr[q] * xd[ll][q];
            float sp = fmaxf(a, 0.f) + log1pf(__expf(-fabsf(a)));
            delta_bf[(size_t)(bl0 + ll) * DI + d] = f2bf(sp);
        }
    }
}

// ---------------------------------------------------------------------------
// K3a: per-chunk local scan (bf16 in, h[16] regs, guarded exp-power trick)
// ---------------------------------------------------------------------------
__global__ __launch_bounds__(256) void k_scanA(const u16* __restrict__ delta_bf,
                                               const float* __restrict__ xdbl,
                                               const u16* __restrict__ u_bf,
                                               const float* __restrict__ A_log,
                                               u16* __restrict__ hend,
                                               float* __restrict__ dsum) {
    __shared__ float Bt[CH][16];
    const int t = threadIdx.x;
    const int d = blockIdx.y * 256 + t;
    const int b = blockIdx.z;
    const int c = blockIdx.x;
    const int l0 = c * CH;
    const size_t bl0 = (size_t)b * LL + l0;
    if (t < CH * 4) {
        int l = t >> 2, n0 = (t & 3) * 4;
        *(float4*)&Bt[l][n0] = *(const float4*)(xdbl + (bl0 + l) * 48 + 16 + n0);
    }
    float Av[16];
    bool fast = true;
    {
        const float4* Ar = (const float4*)(A_log + (size_t)d * 16);
#pragma unroll
        for (int q = 0; q < 4; q++) {
            float4 a = Ar[q];
            Av[q * 4] = -__expf(a.x); Av[q * 4 + 1] = -__expf(a.y);
            Av[q * 4 + 2] = -__expf(a.z); Av[q * 4 + 3] = -__expf(a.w);
        }
#pragma unroll
        for (int n = 0; n < 16; n++)
            fast = fast && (fabsf(Av[n] + (float)(n + 1)) < 1e-4f * (n + 1));
    }
    __syncthreads();
    const u16* dl = delta_bf + bl0 * DI + d;
    const u16* ul = u_bf + bl0 * DI + d;
    float h[16] = {};
    float ds = 0.f;
#pragma unroll 2
    for (int s = 0; s < CH; s++) {
        float de = bf2f(dl[(size_t)s * DI]);
        float uu = bf2f(ul[(size_t)s * DI]);
        float du = de * uu;
        ds += de;
        float pw[16];
        if (fast) {
            float p1 = __expf(-de);
            float p2 = p1 * p1, p4 = p2 * p2, p8 = p4 * p4;
            pw[0] = p1; pw[1] = p2; pw[2] = p2 * p1; pw[3] = p4;
            pw[4] = p4 * p1; pw[5] = p4 * p2; pw[6] = p4 * pw[2]; pw[7] = p8;
            pw[8] = p8 * p1; pw[9] = p8 * p2; pw[10] = p8 * pw[2]; pw[11] = p8 * p4;
            pw[12] = p8 * pw[4]; pw[13] = p8 * pw[5]; pw[14] = p8 * pw[6]; pw[15] = p8 * p8;
        } else {
#pragma unroll
            for (int n = 0; n < 16; n++) pw[n] = __expf(de * Av[n]);
        }
#pragma unroll
        for (int q = 0; q < 4; q++) {
            f32x4 Bv = *(const f32x4*)&Bt[s][q * 4];
#pragma unroll
            for (int j = 0; j < 4; j++) {
                int n = q * 4 + j;
                h[n] = pw[n] * h[n] + du * Bv[j];
            }
        }
    }
    size_t base = ((size_t)b * NC + c) * DI + d;
#pragma unroll
    for (int n = 0; n < 16; n++) hend[base * 16 + n] = f2bf(h[n]);
    dsum[base] = ds;
}

// ---------------------------------------------------------------------------
// K3b: sequential chunk fix-up (bf16 hend/hinit)
// ---------------------------------------------------------------------------
__global__ __launch_bounds__(256) void k_scanB(const float* __restrict__ A_log,
                                               const float* __restrict__ dsum,
                                               const u16* __restrict__ hend,
                                               u16* __restrict__ hinit) {
    int idx = blockIdx.x * 256 + threadIdx.x;
    int n = idx & 15;
    int d = (idx >> 4) & 511;
    int b = idx >> 13;
    float Av = -__expf(A_log[d * 16 + n]);
    float h = 0.f;
    for (int c = 0; c < NC; c++) {
        size_t base = ((size_t)b * NC + c) * DI + d;
        hinit[base * 16 + n] = f2bf(h);
        h = __expf(dsum[base] * Av) * h + bf2f(hend[base * 16 + n]);
    }
}

// ---------------------------------------------------------------------------
// K3c: replay; y[b][l][d] (bf16) = (h.C + D*u)*silu(z)
// ---------------------------------------------------------------------------
__global__ __launch_bounds__(256) void k_scanC(const u16* __restrict__ delta_bf,
                                               const float* __restrict__ xdbl,
                                               const u16* __restrict__ u_bf,
                                               const u16* __restrict__ xz,
                                               const float* __restrict__ A_log,
                                               const float* __restrict__ Dp,
                                               const u16* __restrict__ hinit,
                                               u16* __restrict__ y_bf) {
    __shared__ float Bt[CH][16];
    __shared__ float Ct[CH][16];
    const int t = threadIdx.x;
    const int d = blockIdx.y * 256 + t;
    const int b = blockIdx.z;
    const int c = blockIdx.x;
    const int l0 = c * CH;
    const size_t bl0 = (size_t)b * LL + l0;
    if (t < 128) {
        int l = t >> 2, n0 = (t & 3) * 4;
        *(float4*)&Bt[l][n0] = *(const float4*)(xdbl + (bl0 + l) * 48 + 16 + n0);
    } else {
        int t2 = t - 128;
        int l = t2 >> 2, n0 = (t2 & 3) * 4;
        *(float4*)&Ct[l][n0] = *(const float4*)(xdbl + (bl0 + l) * 48 + 32 + n0);
    }
    float Av[16];
    bool fast = true;
    {
        const float4* Ar = (const float4*)(A_log + (size_t)d * 16);
#pragma unroll
        for (int q = 0; q < 4; q++) {
            float4 a = Ar[q];
            Av[q * 4] = -__expf(a.x); Av[q * 4 + 1] = -__expf(a.y);
            Av[q * 4 + 2] = -__expf(a.z); Av[q * 4 + 3] = -__expf(a.w);
        }
#pragma unroll
        for (int n = 0; n < 16; n++)
            fast = fast && (fabsf(Av[n] + (float)(n + 1)) < 1e-4f * (n + 1));
    }
    float h[16];
    {
        size_t base = ((size_t)b * NC + c) * DI + d;
#pragma unroll
        for (int n = 0; n < 16; n++) h[n] = bf2f(hinit[base * 16 + n]);
    }
    __syncthreads();
    const u16* dl = delta_bf + bl0 * DI + d;
    const u16* ul = u_bf + bl0 * DI + d;
    const u16* zl = xz + bl0 * 1024 + 512 + d;
    u16* yl = y_bf + bl0 * DI + d;
    const float Dv = Dp[d];
#pragma unroll 2
    for (int s = 0; s < CH; s++) {
        float de = bf2f(dl[(size_t)s * DI]);
        float uu = bf2f(ul[(size_t)s * DI]);
        float zz = bf2f(zl[(size_t)s * 1024]);
        float du = de * uu;
        float pw[16];
        if (fast) {
            float p1 = __expf(-de);
            float p2 = p1 * p1, p4 = p2 * p2, p8 = p4 * p4;
            pw[0] = p1; pw[1] = p2; pw[2] = p2 * p1; pw[3] = p4;
            pw[4] = p4 * p1; pw[5] = p4 * p2; pw[6] = p4 * pw[2]; pw[7] = p8;
            pw[8] = p8 * p1; pw[9] = p8 * p2; pw[10] = p8 * pw[2]; pw[11] = p8 * p4;
            pw[12] = p8 * pw[4]; pw[13] = p8 * pw[5]; pw[14] = p8 * pw[6]; pw[15] = p8 * p8;
        } else {
#pragma unroll
            for (int n = 0; n < 16; n++) pw[n] = __expf(de * Av[n]);
        }
        float dot = 0.f;
#pragma unroll
        for (int q = 0; q < 4; q++) {
            f32x4 Bv = *(const f32x4*)&Bt[s][q * 4];
            f32x4 Cv = *(const f32x4*)&Ct[s][q * 4];
#pragma unroll
            for (int j = 0; j < 4; j++) {
                int n = q * 4 + j;
                h[n] = pw[n] * h[n] + du * Bv[j];
                dot += h[n] * Cv[j];
            }
        }
        float sig = 1.f / (1.f + __expf(-zz));
        yl[(size_t)s * DI] = f2bf((dot + Dv * uu) * (zz * sig));
    }
}

// ---------------------------------------------------------------------------
// K4: MFMA GEMM  out[b][o][l] = sum_d W_out[o][d]*y[b][l][d] + x[b][o][l]
// ---------------------------------------------------------------------------
__global__ __launch_bounds__(256) void k_gemm_out(const u16* __restrict__ Wb,
                                                  const u16* __restrict__ yb,
                                                  const float* __restrict__ x,
                                                  float* __restrict__ out) {
    __shared__ short As[64 * 64];
    __shared__ short Bs[128 * 64];
    const int b = blockIdx.z;
    const int l0 = blockIdx.x * 128;
    const int o0 = blockIdx.y * 64;
    const int t = threadIdx.x;
    const int lane = t & 63, wv = t >> 6;
    const u16* ybb = yb + (size_t)b * LL * DI;
    f32x4 acc[4][2] = {};
    for (int k0 = 0; k0 < DI; k0 += 64) {
#pragma unroll
        for (int i = 0; i < 2; i++) {
            int ci = t + i * 256;
            int r = ci >> 3;
            int cb = (ci & 7) * 16;
            int pd = r * 128 + (cb ^ ((r & 7) << 4));
            *(float4*)((char*)As + pd) =
                *(const float4*)((const char*)(Wb + (size_t)(o0 + r) * DI + k0) + cb);
        }
#pragma unroll
        for (int i = 0; i < 4; i++) {
            int ci = t + i * 256;
            int r = ci >> 3;
            int cb = (ci & 7) * 16;
            int pd = r * 128 + (cb ^ ((r & 7) << 4));
            *(float4*)((char*)Bs + pd) =
                *(const float4*)((const char*)(ybb + (size_t)(l0 + r) * DI + k0) + cb);
        }
        __syncthreads();
#pragma unroll
        for (int kk = 0; kk < 2; kk++) {
            const int lcb = kk * 64 + (lane >> 4) * 16;
            bf16x8 af[4], bfr[2];
#pragma unroll
            for (int mi = 0; mi < 4; mi++) {
                int r = mi * 16 + (lane & 15);
                af[mi] = *(const bf16x8*)((const char*)As + r * 128 + (lcb ^ ((r & 7) << 4)));
            }
#pragma unroll
            for (int ni = 0; ni < 2; ni++) {
                int r = wv * 32 + ni * 16 + (lane & 15);
                bfr[ni] = *(const bf16x8*)((const char*)Bs + r * 128 + (lcb ^ ((r & 7) << 4)));
            }
#pragma unroll
            for (int mi = 0; mi < 4; mi++)
#pragma unroll
                for (int ni = 0; ni < 2; ni++)
                    acc[mi][ni] = __builtin_amdgcn_mfma_f32_16x16x32_bf16(
                        af[mi], bfr[ni], acc[mi][ni], 0, 0, 0);
        }
        __syncthreads();
    }
#pragma unroll
    for (int mi = 0; mi < 4; mi++) {
#pragma unroll
        for (int q = 0; q < 4; q++) {
            int o = o0 + mi * 16 + (lane >> 4) * 4 + q;
#pragma unroll
            for (int ni = 0; ni < 2; ni++) {
                int l = l0 + wv * 32 + ni * 16 + (lane & 15);
                size_t a = ((size_t)b * DM + o) * LL + l;
                out[a] = acc[mi][ni][q] + x[a];
            }
        }
    }
}

// ---------------------------------------------------------------------------
extern "C" void kernel_launch(void* const* d_in, const int* in_sizes, int n_in,
                              void* d_out, int out_size, void* d_ws, size_t ws_size,
                              hipStream_t stream) {
    const float* x = (const float*)d_in[0];
    const float* W_in = (const float*)d_in[1];
    const float* W_dw = (const float*)d_in[2];
    const float* b_dw = (const float*)d_in[3];
    const float* W_x = (const float*)d_in[4];
    const float* W_dt = (const float*)d_in[5];
    const float* b_dt = (const float*)d_in[6];
    const float* A_log = (const float*)d_in[7];
    const float* Dp = (const float*)d_in[8];
    const float* W_out = (const float*)d_in[9];
    float* out = (float*)d_out;

    char* p = (char*)d_ws;
    u16* xz_bf = (u16*)p;      p += (size_t)BB * LL * 1024 * 2;    // 16.8 MB
    u16* u_bf = (u16*)p;       p += (size_t)BB * LL * DI * 2;      // 8.4 MB
    u16* delta_bf = (u16*)p;   p += (size_t)BB * LL * DI * 2;      // 8.4 MB
    float* xdbl = (float*)p;   p += (size_t)BB * LL * 48 * 4;      // 1.6 MB
    u16* y_bf = (u16*)p;       p += (size_t)BB * LL * DI * 2;      // 8.4 MB
    float* dsum = (float*)p;   p += (size_t)BB * NC * DI * 4;      // 0.5 MB
    u16* hinit = (u16*)p;      p += (size_t)BB * NC * DI * 16 * 2; // 4.2 MB
    u16* wbf_in = (u16*)p;     p += (size_t)2 * DI * DM * 2;
    u16* wbf_out = (u16*)p;    p += (size_t)DM * DI * 2;
    u16* wbf_x = (u16*)p;      p += (size_t)48 * DI * 2;
    // aliases (lifetime-disjoint):
    u16* xt = delta_bf;  // xt dead (after gemm_in) before k_delta writes delta
    u16* hend = y_bf;    // hend dead (after scanB) before scanC writes y

    k_cvt4<<<(2 * DI * DM / 4 + 255) / 256, 256, 0, stream>>>(W_in, wbf_in,
                                                              2 * DI * DM / 4);
    k_cvt4<<<(DM * DI / 4 + 255) / 256, 256, 0, stream>>>(W_out, wbf_out,
                                                          DM * DI / 4);
    k_cvt4<<<(48 * DI / 4 + 255) / 256, 256, 0, stream>>>(W_x, wbf_x, 48 * DI / 4);
    k_cvt_x<<<dim3(LL / 64, DM / 64, BB), 256, 0, stream>>>(x, xt);
    k_gemm_in<<<dim3(LL / 128, 1024 / 128, BB), 256, 0, stream>>>(xt, wbf_in, xz_bf);
    k_conv<<<(BB * LL * 64) / 256, 256, 0, stream>>>(xz_bf, W_dw, b_dw, u_bf);
    k_xdbl<<<BB * LL / 64, 256, 0, stream>>>(u_bf, wbf_x, xdbl);
    k_delta<<<BB * LL / 16, 256, 0, stream>>>(xdbl, W_dt, b_dt, delta_bf);
    k_scanA<<<dim3(NC, DI / 256, BB), 256, 0, stream>>>(delta_bf, xdbl, u_bf, A_log,
                                                        hend, dsum);
    k_scanB<<<(BB * DI * 16) / 256, 256, 0, stream>>>(A_log, dsum, hend, hinit);
    k_scanC<<<dim3(NC, DI / 256, BB), 256, 0, stream>>>(delta_bf, xdbl, u_bf, xz_bf,
                                                        A_log, Dp, hinit, y_bf);
    k_gemm_out<<<dim3(LL / 128, DM / 64, BB), 256, 0, stream>>>(wbf_out, y_bf, x, out);
}